// Round 8
// baseline (707.800 us; speedup 1.0000x reference)
//
#include <hip/hip_runtime.h>
#include <hip/hip_bf16.h>
#include <math.h>

// ConformHopfieldBatch: B=4 S=2048 IN=64 D=128 HID=400 H=4 K=20 NQ=18
// softmax monotone -> top_k(assoc) == top_k(raw scores). bf16-hi MFMA
// PREFILTER -> approx candidates; exact fp32 RESCORE -> true top-20 (R2).
// Ladder: R13 (LDS bcast, 4 waves/SIMD, VGPR64) = 278us k_mlp BEST.
// R15 (8 waves/SIMD via (256,8)): 356 -- VGPR crushed to 32, serialized.
// R16 (paired loads, -VALU ops): 294 -- slower. R19 (4x fewer ds_read,
// 3x weight traffic): 330, VALU 47 -- slower. Conclusion: time
// anti-correlates with VALU-op count => latency-stall-bound; R13 mix is
// ~67% FMA-of-issue (matches VALUBusy 67) with ~25% unhidden stall at
// only 4 waves/SIMD.
// R20: R13's EXACT per-wave structure (scalar weight loads, col-slice
// per wave) at 6 waves/SIMD: ROWS=8 (12.8KB LDS -> 6 blocks/CU), grid
// 2048, launch_bounds(256,6) -> VGPR cap 84 >= the 64 R13 used (R15's
// confound removed). Keep R16 slice rotation + k_select reg-argmax.
// Per-column FMA i-order unchanged -> outputs bit-identical.

#define SS 2048
#define ROWS 8
#define AST 400   // LDS activation row stride (floats)

typedef short short8v __attribute__((ext_vector_type(8)));
typedef float float4v __attribute__((ext_vector_type(4)));
typedef float float2v __attribute__((ext_vector_type(2)));

__constant__ float c_alphas[18] = {0.05f,0.06f,0.08f,0.1f,0.12f,0.14f,0.15f,0.17f,
                                   0.19f,0.2f,0.21f,0.23f,0.25f,0.3f,0.35f,0.38f,0.4f,0.45f};

// output flat offsets (return-order concat)
#define OFF_Y      1
#define OFF_YPRED  32769
#define OFF_YLOW   65537ll
#define OFF_YHIGH  655361ll
#define OFF_ERR    1245185ll
#define OFF_QLOW   1253377ll
#define OFF_QHIGH  1843201ll

__device__ inline short f2bf_s(float f) {
    __hip_bfloat16 h = __float2bfloat16(f);
    return __builtin_bit_cast(short, h);
}
// monotone fp32 -> u32 map (order-preserving)
__device__ inline unsigned mono(float f) {
    unsigned u = __builtin_bit_cast(unsigned, f);
    return (u & 0x80000000u) ? ~u : (u | 0x80000000u);
}
__device__ inline unsigned umin_(unsigned a, unsigned b) { return a < b ? a : b; }
__device__ inline unsigned umax_(unsigned a, unsigned b) { return a > b ? a : b; }

// ---------------------------------------------------------------------------
// Kernel A: fused MLP + LayerNorm + projection. 256 threads (4 waves),
// 8 rows/block, grid 2048 -> 6 blocks/CU resident (launch_bounds 256,6).
// Activations in LDS (12.8KB); x broadcast via uniform ds_read_b128.
// Column split: wave's slice rotates per block (sl=(w+bi)&3); lane owns
// cols {sl*128 + cc*64 + t, cc=0,1} with clamp-to-399 dummies in the
// 400-wide layers (slice 3). Scalar weight loads (R13 style -- the
// fastest measured mix). FMA i-order per column identical to R13.
// ---------------------------------------------------------------------------

template<int IN_W, int NCC>
__device__ __forceinline__ void mlp_layer_acc(
    const float* __restrict__ W, const float* __restrict__ act,
    const int jm0, const int jm1, float (&acc)[ROWS][2])
{
    #pragma unroll
    for (int r = 0; r < ROWS; ++r)
        #pragma unroll
        for (int cc = 0; cc < NCC; ++cc) acc[r][cc] = 0.f;

    #pragma unroll 2
    for (int i4 = 0; i4 < IN_W/4; ++i4) {
        float wv[4][2];
        #pragma unroll
        for (int jj = 0; jj < 4; ++jj) {
            wv[jj][0] = W[(i4*4 + jj)*400 + jm0];
            if (NCC > 1) wv[jj][1] = W[(i4*4 + jj)*400 + jm1];
        }
        #pragma unroll
        for (int r = 0; r < ROWS; ++r) {
            const float4v xv = *(const float4v*)(act + r*AST + i4*4);
            #pragma unroll
            for (int jj = 0; jj < 4; ++jj)
                #pragma unroll
                for (int cc = 0; cc < NCC; ++cc)
                    acc[r][cc] = fmaf(xv[jj], wv[jj][cc], acc[r][cc]);
        }
    }
}

__device__ __forceinline__ void mlp_layer_store(
    const float* __restrict__ b, float* __restrict__ act,
    const int jm0, const int jm1, const bool on0, const bool on1,
    const float (&acc)[ROWS][2])
{
    if (on0) {
        const float bv = b[jm0];
        #pragma unroll
        for (int r = 0; r < ROWS; ++r)
            act[r*AST + jm0] = fmaxf(acc[r][0] + bv, 0.f);
    }
    if (on1) {
        const float bv = b[jm1];
        #pragma unroll
        for (int r = 0; r < ROWS; ++r)
            act[r*AST + jm1] = fmaxf(acc[r][1] + bv, 0.f);
    }
}

__global__ __launch_bounds__(256, 6) void k_mlp(
    const float* __restrict__ Xt, const float* __restrict__ Xs,
    const float* __restrict__ W1, const float* __restrict__ b1,
    const float* __restrict__ W2, const float* __restrict__ b2,
    const float* __restrict__ W3, const float* __restrict__ b3,
    const float* __restrict__ W4, const float* __restrict__ b4,
    const float* __restrict__ Wq, const float* __restrict__ bq,
    const float* __restrict__ Wk, const float* __restrict__ bk,
    const float* __restrict__ g_q, const float* __restrict__ beta_q,
    const float* __restrict__ g_k, const float* __restrict__ beta_k,
    float* __restrict__ qf, float* __restrict__ kf,
    __hip_bfloat16* __restrict__ khi)
{
    __shared__ float act[ROWS*AST];          // 12.8 KB

    const int tid  = threadIdx.x;
    const int t    = tid & 63;
    const int w    = tid >> 6;               // wave 0..3
    const int bi   = blockIdx.x;
    const int half = bi >> 10;               // 0:true/q 1:sim/k
    const int rbase = (bi & 1023) * ROWS;
    const float* X = half ? Xs : Xt;

    const int sl  = (w + bi) & 3;            // rotated col slice
    const int j0  = sl*128 + t;              // cc=0 col
    const int j1  = sl*128 + 64 + t;         // cc=1 col
    const int jm0 = (j0 < 400) ? j0 : 399;   // clamped (dummy discarded)
    const int jm1 = (j1 < 400) ? j1 : 399;
    const bool on0 = (j0 < 400);
    const bool on1 = (j1 < 400);
    const bool s3  = (sl == 3);

    // stage input rows (8 x 64, coalesced)
    #pragma unroll
    for (int u = 0; u < (ROWS*64)/256; ++u) {
        const int e = u*256 + tid;
        act[(e >> 6)*AST + (e & 63)] = X[(size_t)rbase*64 + e];
    }
    __syncthreads();

    float acc[ROWS][2];

    // ---- layer 1: 64 -> 400 (relu) ----
    if (s3) mlp_layer_acc<64,1>(W1, act, jm0, jm1, acc);
    else    mlp_layer_acc<64,2>(W1, act, jm0, jm1, acc);
    __syncthreads();
    mlp_layer_store(b1, act, jm0, jm1, on0, on1 && !s3, acc);
    __syncthreads();

    // ---- layer 2: 400 -> 400 (relu) ----
    if (s3) mlp_layer_acc<400,1>(W2, act, jm0, jm1, acc);
    else    mlp_layer_acc<400,2>(W2, act, jm0, jm1, acc);
    __syncthreads();
    mlp_layer_store(b2, act, jm0, jm1, on0, on1 && !s3, acc);
    __syncthreads();

    // ---- layer 3: 400 -> 400 (relu) ----
    if (s3) mlp_layer_acc<400,1>(W3, act, jm0, jm1, acc);
    else    mlp_layer_acc<400,2>(W3, act, jm0, jm1, acc);
    __syncthreads();
    mlp_layer_store(b3, act, jm0, jm1, on0, on1 && !s3, acc);
    __syncthreads();

    // ---- layer 4: 400 -> 128 (no relu). Row-split: wave w rows 2w..2w+1,
    //      lane owns col pair (t, 64+t) -- exact R13 mapping/i-order. ----
    float2v a4[2];
    #pragma unroll
    for (int rr = 0; rr < 2; ++rr) a4[rr] = (float2v){0.f, 0.f};
    #pragma unroll 2
    for (int i4 = 0; i4 < 100; ++i4) {
        float wv0[4], wv1[4];
        #pragma unroll
        for (int jj = 0; jj < 4; ++jj) {
            wv0[jj] = W4[(i4*4 + jj)*128 + t];
            wv1[jj] = W4[(i4*4 + jj)*128 + 64 + t];
        }
        #pragma unroll
        for (int rr = 0; rr < 2; ++rr) {
            const float4v xv = *(const float4v*)(act + (w*2 + rr)*AST + i4*4);
            #pragma unroll
            for (int jj = 0; jj < 4; ++jj) {
                a4[rr][0] = fmaf(xv[jj], wv0[jj], a4[rr][0]);
                a4[rr][1] = fmaf(xv[jj], wv1[jj], a4[rr][1]);
            }
        }
    }
    {
        const float b40 = b4[t], b41 = b4[64 + t];
        #pragma unroll
        for (int rr = 0; rr < 2; ++rr) { a4[rr][0] += b40; a4[rr][1] += b41; }
    }
    __syncthreads();                         // all L4 reads of act complete

    // ---- LayerNorm over 128 (2 vals/lane, same 64-lane butterfly) ----
    {
        const float* g  = half ? g_k : g_q;
        const float* be = half ? beta_k : beta_q;
        const float gl0 = g[t],  gl1 = g[64 + t];
        const float bl0 = be[t], bl1 = be[64 + t];
        #pragma unroll
        for (int rr = 0; rr < 2; ++rr) {
            float s = a4[rr][0] + a4[rr][1];
            #pragma unroll
            for (int o = 32; o > 0; o >>= 1) s += __shfl_xor(s, o);
            const float mu = s * (1.f/128.f);
            const float d0 = a4[rr][0] - mu, d1 = a4[rr][1] - mu;
            float vs = d0*d0 + d1*d1;
            #pragma unroll
            for (int o = 32; o > 0; o >>= 1) vs += __shfl_xor(vs, o);
            const float rstd = rsqrtf(vs * (1.f/128.f) + 1e-5f);
            act[(w*2 + rr)*128 + t]      = d0*rstd*gl0 + bl0;
            act[(w*2 + rr)*128 + 64 + t] = d1*rstd*gl1 + bl1;
        }
    }
    __syncthreads();

    // ---- projection 128 -> 512, col slice (all cols real) ----
    {
        const float* Wp = half ? Wk : Wq;
        const float* bp = half ? bk : bq;
        float* of = half ? kf : qf;

        float accp[ROWS][2];
        #pragma unroll
        for (int r = 0; r < ROWS; ++r) { accp[r][0] = 0.f; accp[r][1] = 0.f; }
        #pragma unroll 2
        for (int i4 = 0; i4 < 32; ++i4) {
            float wv[4][2];
            #pragma unroll
            for (int jj = 0; jj < 4; ++jj) {
                wv[jj][0] = Wp[(i4*4 + jj)*512 + j0];
                wv[jj][1] = Wp[(i4*4 + jj)*512 + j1];
            }
            #pragma unroll
            for (int r = 0; r < ROWS; ++r) {
                const float4v xv = *(const float4v*)(act + r*128 + i4*4);
                #pragma unroll
                for (int jj = 0; jj < 4; ++jj) {
                    accp[r][0] = fmaf(xv[jj], wv[jj][0], accp[r][0]);
                    accp[r][1] = fmaf(xv[jj], wv[jj][1], accp[r][1]);
                }
            }
        }

        const float bp0 = bp[j0], bp1 = bp[j1];
        #pragma unroll
        for (int r = 0; r < ROWS; ++r) {
            const int gidx = rbase + r;
            const int bB = gidx >> 11, s = gidx & 2047;
            const int T = s >> 4, m16s = s & 15;
            #pragma unroll
            for (int cc = 0; cc < 2; ++cc) {
                const int j  = cc ? j1 : j0;
                const int hh = j >> 7, d = j & 127;
                const float v = (cc ? accp[r][1] : accp[r][0]) + (cc ? bp1 : bp0);
                const size_t dst = ((size_t)(bB*4 + hh)*2048 + s)*128 + d;
                of[dst] = v;
                if (half) {
                    const int ks = d >> 5, qd = (d & 31) >> 3, jj = d & 7;
                    const size_t so = (size_t)(bB*4 + hh)*262144
                                    + (size_t)T*2048 + ks*512 + qd*128 + m16s*8 + jj;
                    khi[so] = __float2bfloat16(v);
                }
            }
        }
    }
}

// ---------------------------------------------------------------------------
// Kernel B: MFMA scan over an m-quarter (512 cols). Per lane: two independent
// sorted depth-12 key lists (2-way ILP); owner (quad0) 8-way tournament merge
// -> top-24 -> wsk. khi fragment-swizzled (contiguous 1KB/wave loads).
// ---------------------------------------------------------------------------
__global__ __launch_bounds__(256, 4) void k_scan(
    const float* __restrict__ qf, const __hip_bfloat16* __restrict__ khi,
    unsigned* __restrict__ wsk)
{
    __shared__ unsigned kd[64*97];     // 24.8KB; row stride 97 (odd) bank-safe

    const int tid   = threadIdx.x;
    const int stile = blockIdx.x;      // 0..31
    const int hb    = blockIdx.y;      // 0..15
    const int mq    = blockIdx.z;      // 0..3

    const int lane = tid & 63;
    const int w    = tid >> 6;
    const int m16  = lane & 15;
    const int quad = lane >> 4;

    const size_t slab = (size_t)hb * 2048;
    const __hip_bfloat16* slabp = khi + (size_t)hb * 262144;   // swizzled slab

    const int sg_my = stile*64 + w*16 + m16;

    // Q fragment (B operand): B[n=m16][k=quad*8+j+ks*32] = q[w*16+n][k]
    short8v bq_[4];
    {
        const float* qp = qf + (slab + sg_my)*128 + quad*8;
        #pragma unroll
        for (int ks = 0; ks < 4; ++ks) {
            const float4 x0 = *(const float4*)(qp + ks*32);
            const float4 x1 = *(const float4*)(qp + ks*32 + 4);
            short8v tt;
            tt[0]=f2bf_s(x0.x); tt[1]=f2bf_s(x0.y); tt[2]=f2bf_s(x0.z); tt[3]=f2bf_s(x0.w);
            tt[4]=f2bf_s(x1.x); tt[5]=f2bf_s(x1.y); tt[6]=f2bf_s(x1.z); tt[7]=f2bf_s(x1.w);
            bq_[ks] = tt;
        }
    }

    unsigned KA[12], KB[12];           // ascending; [0] = min
    #pragma unroll
    for (int n = 0; n < 12; ++n) { KA[n] = 0u; KB[n] = 0u; }

    #pragma unroll 1
    for (int cti = 0; cti < 32; ++cti) {
        const int T = mq*32 + cti;     // global 16-col tile id
        const __hip_bfloat16* kp = slabp + (size_t)T*2048 + lane*8;
        float4v acc = (float4v){0.f,0.f,0.f,0.f};
        #pragma unroll
        for (int ks = 0; ks < 4; ++ks) {
            const short8v ka = *(const short8v*)(kp + ks*512);
            acc = __builtin_amdgcn_mfma_f32_16x16x32_bf16(ka, bq_[ks], acc, 0, 0, 0);
        }
        const int cb = T*16 + quad*4;
        #pragma unroll
        for (int ph = 0; ph < 2; ++ph) {
            {   // KA insert: reg = ph
                const int m = cb + ph;
                unsigned key = (mono(acc[ph]) & 0xFFFFF800u) | (unsigned)m;
                key = (m == sg_my) ? 0u : key;
                KA[0] = umax_(KA[0], key);
                #pragma unroll
                for (int i = 0; i < 11; ++i) {
                    const unsigned a = KA[i], c = KA[i+1];
                    KA[i]   = umin_(a, c);
                    KA[i+1] = umax_(a, c);
                }
            }
            {   // KB insert: reg = 2+ph
                const int m = cb + 2 + ph;
                unsigned key = (mono(acc[2+ph]) & 0xFFFFF800u) | (unsigned)m;
                key = (m == sg_my) ? 0u : key;
                KB[0] = umax_(KB[0], key);
                #pragma unroll
                for (int i = 0; i < 11; ++i) {
                    const unsigned a = KB[i], c = KB[i+1];
                    KB[i]   = umin_(a, c);
                    KB[i+1] = umax_(a, c);
                }
            }
        }
    }

    // dump: per (row, quad) two desc 12-lists
    const int rr = w*16 + m16;
    #pragma unroll
    for (int n = 0; n < 12; ++n) {
        kd[rr*97 + (quad*2 + 0)*12 + n] = KA[11 - n];
        kd[rr*97 + (quad*2 + 1)*12 + n] = KB[11 - n];
    }
    __syncthreads();

    // owner (quad 0): 8-way tournament merge -> top-24 -> ws (desc).
    if (quad == 0) {
        const unsigned* R = &kd[rr*97];
        int q0=0,q1=0,q2=0,q3=0,q4=0,q5=0,q6=0,q7=0;
        const size_t base = (size_t)hb*2048 + stile*64 + rr;
        #pragma unroll 1
        for (int n = 0; n < 24; ++n) {
            const unsigned h0 = (q0<12)?R[  0+q0]:0u;
            const unsigned h1 = (q1<12)?R[ 12+q1]:0u;
            const unsigned h2 = (q2<12)?R[ 24+q2]:0u;
            const unsigned h3 = (q3<12)?R[ 36+q3]:0u;
            const unsigned h4 = (q4<12)?R[ 48+q4]:0u;
            const unsigned h5 = (q5<12)?R[ 60+q5]:0u;
            const unsigned h6 = (q6<12)?R[ 72+q6]:0u;
            const unsigned h7 = (q7<12)?R[ 84+q7]:0u;
            unsigned bv = h0; int bs = 0;
            if (h1 > bv) { bv = h1; bs = 1; }
            if (h2 > bv) { bv = h2; bs = 2; }
            if (h3 > bv) { bv = h3; bs = 3; }
            if (h4 > bv) { bv = h4; bs = 4; }
            if (h5 > bv) { bv = h5; bs = 5; }
            if (h6 > bv) { bv = h6; bs = 6; }
            if (h7 > bv) { bv = h7; bs = 7; }
            q0 += (bs==0); q1 += (bs==1); q2 += (bs==2); q3 += (bs==3);
            q4 += (bs==4); q5 += (bs==5); q6 += (bs==6); q7 += (bs==7);
            wsk[(size_t)(mq*24 + n)*32768 + base] = bv;
        }
    }
}

// ---------------------------------------------------------------------------
// Kernel C: per row merge 4x24 approx keys -> top-32 -> cooperative exact
// fp32 rescore -> exact top-20 (register argmax, identical compare order)
// -> batched error gathers -> quantiles + outputs.
// ---------------------------------------------------------------------------
__global__ __launch_bounds__(256, 2) void k_select(
    const float* __restrict__ qf, const float* __restrict__ kf,
    const unsigned* __restrict__ wsk,
    const float* __restrict__ errors, const float* __restrict__ y,
    const float* __restrict__ y_pred,
    float* __restrict__ out, float* __restrict__ hacc)
{
    __shared__ unsigned kd[64*4*25];       // 25.6KB (pad 25)
    __shared__ unsigned short cb[64*33];   // 4.2KB candidate cols
    __shared__ float es[64*33];            // 8.4KB exact scores
    __shared__ float ebuf[64*21];          // 5.4KB sort buffer

    const int tid   = threadIdx.x;
    const int stile = blockIdx.x;          // 0..31
    const int hb    = blockIdx.y;          // 0..15
    const int b     = hb >> 2;
    const int h     = hb & 3;

    const int lane = tid & 63;
    const int w    = tid >> 6;
    const int m16  = lane & 15;
    const int quad = lane >> 4;
    const int rr   = w*16 + m16;
    const int sg   = stile*64 + rr;

    const size_t base = (size_t)hb*2048 + sg;
    #pragma unroll 1
    for (int n = 0; n < 24; ++n)
        kd[(rr*4 + quad)*25 + n] = wsk[(size_t)(quad*24 + n)*32768 + base];
    __syncthreads();

    // owner: merge 4 sorted-desc 24-lists -> approx-top-32 cols
    if (quad == 0) {
        const unsigned* L0 = &kd[(rr*4 + 0)*25];
        const unsigned* L1 = &kd[(rr*4 + 1)*25];
        const unsigned* L2 = &kd[(rr*4 + 2)*25];
        const unsigned* L3 = &kd[(rr*4 + 3)*25];
        int p0 = 0, p1 = 0, p2 = 0, p3 = 0;
        #pragma unroll 1
        for (int n = 0; n < 32; ++n) {
            const unsigned h0 = (p0 < 24) ? L0[p0] : 0u;
            const unsigned h1 = (p1 < 24) ? L1[p1] : 0u;
            const unsigned h2 = (p2 < 24) ? L2[p2] : 0u;
            const unsigned h3 = (p3 < 24) ? L3[p3] : 0u;
            unsigned bv = h0; int bs = 0;
            if (h1 > bv) { bv = h1; bs = 1; }
            if (h2 > bv) { bv = h2; bs = 2; }
            if (h3 > bv) { bv = h3; bs = 3; }
            if (bs == 0) ++p0; else if (bs == 1) ++p1; else if (bs == 2) ++p2; else ++p3;
            cb[rr*33 + n] = (unsigned short)(bv & 0x7FFu);
        }
    }
    __syncthreads();

    // cooperative exact rescore of the 32 candidates (pk-packed partials)
    const size_t slab = (size_t)hb * 2048;
    const float* qrow_p = qf + (slab + sg)*128;
    float4 qseg[8];
    #pragma unroll
    for (int u = 0; u < 8; ++u)
        qseg[u] = *(const float4*)(qrow_p + quad*4 + u*16);
    const float* kslab = kf + slab*128;
    #pragma unroll 1
    for (int n = 0; n < 32; ++n) {
        const int col = cb[rr*33 + n];
        const float* kc = kslab + (size_t)col*128 + quad*4;
        float2v s01 = (float2v){0.f, 0.f}, s23 = (float2v){0.f, 0.f};
        #pragma unroll
        for (int u = 0; u < 8; ++u) {
            const float4 kv = *(const float4*)(kc + u*16);
            s01 = __builtin_elementwise_fma((float2v){qseg[u].x, qseg[u].y},
                                            (float2v){kv.x, kv.y}, s01);
            s23 = __builtin_elementwise_fma((float2v){qseg[u].z, qseg[u].w},
                                            (float2v){kv.z, kv.w}, s23);
        }
        float v = (s01[0] + s01[1]) + (s23[0] + s23[1]);
        v += __shfl_xor(v, 16);
        v += __shfl_xor(v, 32);
        if (quad == 0) es[rr*33 + n] = v;
    }

    // owner: exact top-20 selection in registers (desc, col asc ties)
    float sq = 0.f;
    if (quad == 0) {
        float rv[32]; int cvv[32];
        #pragma unroll
        for (int j = 0; j < 32; ++j) {
            rv[j]  = es[rr*33 + j];
            cvv[j] = (int)cb[rr*33 + j];
        }
        int bcs[20];
        #pragma unroll
        for (int k = 0; k < 20; ++k) {
            float best = -INFINITY; int bc = 4096, bj = 0;
            #pragma unroll
            for (int j = 0; j < 32; ++j) {
                const bool tk = (rv[j] > best) || (rv[j] == best && cvv[j] < bc);
                best = tk ? rv[j]  : best;
                bc   = tk ? cvv[j] : bc;
                bj   = tk ? j      : bj;
            }
            #pragma unroll
            for (int j = 0; j < 32; ++j)
                rv[j] = (j == bj) ? -INFINITY : rv[j];
            bcs[k] = bc;
        }
        float* e = &ebuf[rr*21];
        #pragma unroll
        for (int k = 0; k < 20; ++k)
            e[k] = errors[((size_t)(b*SS + bcs[k]))*4];   // errors[..., 0]
        #pragma unroll 1
        for (int a = 1; a < 20; ++a) {     // insertion sort ascending
            const float v = e[a];
            int n = a;
            while (n > 0 && e[n-1] > v) { e[n] = e[n-1]; --n; }
            e[n] = v;
        }
        const float yp = y_pred[((size_t)(b*SS + sg))*4];
        const float yt = y[((size_t)(b*SS + sg))*4];
        float msum = 0.f;
        const size_t obase = ((size_t)(h*4 + b)*18)*2048 + sg;
        #pragma unroll 1
        for (int a = 0; a < 18; ++a) {
            const float alpha = c_alphas[a];
            const float beta  = 0.5f*alpha;
            const float pl = beta * 19.f;
            const int   il = (int)pl;
            const float fl = pl - (float)il;
            const float ql = e[il]*(1.f-fl) + e[il+1]*fl;
            const float qq = (1.f - alpha) + beta;
            const float ph = qq * 19.f;
            const int   ih = (int)ph;
            const float fh = ph - (float)ih;
            const float qh = e[ih]*(1.f-fh) + e[ih+1]*fh;
            msum += ql + qh;
            const size_t oidx = obase + (size_t)a*2048;
            out[OFF_YLOW  + oidx] = ql + yp;
            out[OFF_YHIGH + oidx] = qh + yp;
            out[OFF_QLOW  + oidx] = ql;
            out[OFF_QHIGH + oidx] = qh;
        }
        const float me = msum * (1.f/36.f);
        const float dd = yt - (me + yp);
        sq = dd*dd;
    }
    // wave-reduce sq (non-owners contribute 0), one atomic per wave
    #pragma unroll
    for (int o = 32; o > 0; o >>= 1) sq += __shfl_xor(sq, o);
    if (lane == 0) atomicAdd(&hacc[h], sq);
}

__global__ void k_init(float* __restrict__ hacc) {
    if (threadIdx.x < 4) hacc[threadIdx.x] = 0.f;
}

__global__ __launch_bounds__(256) void k_finalize(
    const float* __restrict__ y, const float* __restrict__ y_pred,
    const float* __restrict__ errors, const float* __restrict__ hacc,
    float* __restrict__ out)
{
    const int i = blockIdx.x*256 + threadIdx.x;
    if (i == 0)
        out[0] = (hacc[0]+hacc[1]+hacc[2]+hacc[3]) * (1.f/32768.f);
    if (i < 32768)      out[OFF_Y + i] = y[i];
    else if (i < 65536) out[OFF_YPRED + (i - 32768)] = y_pred[i - 32768];
    else if (i < 73728) { const int j = i - 65536; out[OFF_ERR + j] = errors[(size_t)j*4]; }
}

extern "C" void kernel_launch(void* const* d_in, const int* in_sizes, int n_in,
                              void* d_out, int out_size, void* d_ws, size_t ws_size,
                              hipStream_t stream)
{
    const float* Xt     = (const float*)d_in[0];
    const float* Xs     = (const float*)d_in[1];
    const float* errors = (const float*)d_in[2];
    const float* y      = (const float*)d_in[3];
    const float* y_pred = (const float*)d_in[4];
    const float* W1 = (const float*)d_in[5];   const float* b1 = (const float*)d_in[6];
    const float* W2 = (const float*)d_in[7];   const float* b2 = (const float*)d_in[8];
    const float* W3 = (const float*)d_in[9];   const float* b3 = (const float*)d_in[10];
    const float* W4 = (const float*)d_in[11];  const float* b4 = (const float*)d_in[12];
    const float* Wq = (const float*)d_in[13];  const float* bq = (const float*)d_in[14];
    const float* Wk = (const float*)d_in[15];  const float* bk = (const float*)d_in[16];
    const float* g_q    = (const float*)d_in[17];
    const float* beta_q = (const float*)d_in[18];
    const float* g_k    = (const float*)d_in[19];
    const float* beta_k = (const float*)d_in[20];

    float* out  = (float*)d_out;
    char*  base = (char*)d_ws;
    const size_t SLAB = (size_t)16*2048*128;               // 4,194,304 elements
    float* hacc = (float*)base;                            // 64B slot
    float* qf   = (float*)(base + 256);                    // 16MB
    float* kf   = qf + SLAB;                               // 16MB
    __hip_bfloat16* khi = (__hip_bfloat16*)(kf + SLAB);    // 8MB (swizzled)
    unsigned* wsk = (unsigned*)(khi + SLAB);               // 12.6MB

    k_init<<<1, 64, 0, stream>>>(hacc);
    k_mlp<<<2048, 256, 0, stream>>>(Xt, Xs, W1,b1,W2,b2,W3,b3,W4,b4,
                                    Wq,bq,Wk,bk,g_q,beta_q,g_k,beta_k,
                                    qf, kf, khi);
    k_scan<<<dim3(32,16,4), 256, 0, stream>>>(qf, khi, wsk);
    k_select<<<dim3(32,16), 256, 0, stream>>>(qf, kf, wsk, errors, y, y_pred, out, hacc);
    k_finalize<<<288, 256, 0, stream>>>(y, y_pred, errors, hacc, out);
}

// Round 9
// 631.150 us; speedup vs baseline: 1.1214x; 1.1214x over previous
//
#include <hip/hip_runtime.h>
#include <hip/hip_bf16.h>
#include <math.h>

// ConformHopfieldBatch: B=4 S=2048 IN=64 D=128 HID=400 H=4 K=20 NQ=18
// softmax monotone -> top_k(assoc) == top_k(raw scores). bf16-hi MFMA
// PREFILTER -> approx candidates; exact fp32 RESCORE -> true top-20 (R2).
// Session law (R13..R20): k_mlp time tracks VGPR headroom, NOT occupancy
// (40->54->80% never helped) and NOT VALU-op count (R16/R19 op cuts both
// regressed). VGPR: 108->361us, 64->278 (BEST, R14), 52->330, 36->455,
// 32->356. Model: in-wave latency-bound -- 64 VGPR holds only ~1 K-step
// of in-flight loads; steps end in vmcnt/lgkmcnt waits that 3-4
// waves/SIMD partially cover.
// R21: exact R14 source (best known, 610.66us wall) with ONE change:
// i4-loop unroll 2 -> 4 (mlp layers, L4, projection) to double in-flight
// loads under the proven (256,4) bound (VGPR cap 128 -- headroom, not
// starvation). Unroll does not reorder per-column FMA chains -> outputs
// bit-identical. k_scan/k_select/k_finalize byte-identical to R14.

#define SS 2048
#define ROWS 16
#define AST 400   // LDS activation row stride (floats); 1600B, 16B-aligned

typedef short short8v __attribute__((ext_vector_type(8)));
typedef float float4v __attribute__((ext_vector_type(4)));
typedef float float2v __attribute__((ext_vector_type(2)));

__constant__ float c_alphas[18] = {0.05f,0.06f,0.08f,0.1f,0.12f,0.14f,0.15f,0.17f,
                                   0.19f,0.2f,0.21f,0.23f,0.25f,0.3f,0.35f,0.38f,0.4f,0.45f};

// output flat offsets (return-order concat)
#define OFF_Y      1
#define OFF_YPRED  32769
#define OFF_YLOW   65537ll
#define OFF_YHIGH  655361ll
#define OFF_ERR    1245185ll
#define OFF_QLOW   1253377ll
#define OFF_QHIGH  1843201ll

__device__ inline short f2bf_s(float f) {
    __hip_bfloat16 h = __float2bfloat16(f);
    return __builtin_bit_cast(short, h);
}
// monotone fp32 -> u32 map (order-preserving)
__device__ inline unsigned mono(float f) {
    unsigned u = __builtin_bit_cast(unsigned, f);
    return (u & 0x80000000u) ? ~u : (u | 0x80000000u);
}
__device__ inline unsigned umin_(unsigned a, unsigned b) { return a < b ? a : b; }
__device__ inline unsigned umax_(unsigned a, unsigned b) { return a > b ? a : b; }

// ---------------------------------------------------------------------------
// Kernel A: fused MLP + LayerNorm + projection. 256 threads (4 waves),
// 16 rows/block, grid 1024. Activations in LDS; x broadcast via uniform
// ds_read_b128; weights streamed coalesced. Column-split across waves for
// 400/512-wide layers; row-split for L4+LN. Per-column FMA order identical
// to R12..R14 -> bit-identical outputs.
// ---------------------------------------------------------------------------

template<int IN_W, int NCC>
__device__ __forceinline__ void mlp_layer_acc(
    const float* __restrict__ W, const float* __restrict__ act,
    const int w, const int t, float (&acc)[ROWS][2])
{
    int jm[2];
    #pragma unroll
    for (int cc = 0; cc < NCC; ++cc) {
        const int j = w*128 + cc*64 + t;
        jm[cc] = (j < 400) ? j : 399;      // clamped dummy (discarded at store)
    }
    #pragma unroll
    for (int r = 0; r < ROWS; ++r)
        #pragma unroll
        for (int cc = 0; cc < NCC; ++cc) acc[r][cc] = 0.f;

    #pragma unroll 4
    for (int i4 = 0; i4 < IN_W/4; ++i4) {
        float wv[4][2];
        #pragma unroll
        for (int jj = 0; jj < 4; ++jj)
            #pragma unroll
            for (int cc = 0; cc < NCC; ++cc)
                wv[jj][cc] = W[(i4*4 + jj)*400 + jm[cc]];
        #pragma unroll
        for (int r = 0; r < ROWS; ++r) {
            const float4v xv = *(const float4v*)(act + r*AST + i4*4);
            #pragma unroll
            for (int jj = 0; jj < 4; ++jj)
                #pragma unroll
                for (int cc = 0; cc < NCC; ++cc)
                    acc[r][cc] = fmaf(xv[jj], wv[jj][cc], acc[r][cc]);
        }
    }
}

__device__ __forceinline__ void mlp_layer_store(
    const float* __restrict__ b, float* __restrict__ act,
    const int w, const int t, const int ncc, const float (&acc)[ROWS][2])
{
    #pragma unroll
    for (int cc = 0; cc < 2; ++cc) {          // static cc -> no scratch
        const int j = w*128 + cc*64 + t;
        if (cc < ncc && j < 400) {
            const float bv = b[j];
            #pragma unroll
            for (int r = 0; r < ROWS; ++r)
                act[r*AST + j] = fmaxf(acc[r][cc] + bv, 0.f);
        }
    }
}

__global__ __launch_bounds__(256, 4) void k_mlp(
    const float* __restrict__ Xt, const float* __restrict__ Xs,
    const float* __restrict__ W1, const float* __restrict__ b1,
    const float* __restrict__ W2, const float* __restrict__ b2,
    const float* __restrict__ W3, const float* __restrict__ b3,
    const float* __restrict__ W4, const float* __restrict__ b4,
    const float* __restrict__ Wq, const float* __restrict__ bq,
    const float* __restrict__ Wk, const float* __restrict__ bk,
    const float* __restrict__ g_q, const float* __restrict__ beta_q,
    const float* __restrict__ g_k, const float* __restrict__ beta_k,
    float* __restrict__ qf, float* __restrict__ kf,
    __hip_bfloat16* __restrict__ khi)
{
    __shared__ float act[ROWS*AST];          // 25.6 KB

    const int tid  = threadIdx.x;
    const int t    = tid & 63;
    const int w    = tid >> 6;               // wave 0..3
    const int bi   = blockIdx.x;
    const int half = bi >> 9;                // 0:true/q 1:sim/k
    const int rbase = (bi & 511) * ROWS;
    const float* X = half ? Xs : Xt;

    // stage input rows (16 x 64, coalesced)
    #pragma unroll
    for (int u = 0; u < (ROWS*64)/256; ++u) {
        const int e = u*256 + tid;
        act[(e >> 6)*AST + (e & 63)] = X[(size_t)rbase*64 + e];
    }
    __syncthreads();

    float acc[ROWS][2];
    const int ncc = (w == 3) ? 1 : 2;        // wave3: cols 448..511 all dummy

    // ---- layer 1: 64 -> 400 (relu) ----
    if (w == 3) mlp_layer_acc<64,1>(W1, act, w, t, acc);
    else        mlp_layer_acc<64,2>(W1, act, w, t, acc);
    __syncthreads();
    mlp_layer_store(b1, act, w, t, ncc, acc);
    __syncthreads();

    // ---- layer 2: 400 -> 400 (relu) ----
    if (w == 3) mlp_layer_acc<400,1>(W2, act, w, t, acc);
    else        mlp_layer_acc<400,2>(W2, act, w, t, acc);
    __syncthreads();
    mlp_layer_store(b2, act, w, t, ncc, acc);
    __syncthreads();

    // ---- layer 3: 400 -> 400 (relu) ----
    if (w == 3) mlp_layer_acc<400,1>(W3, act, w, t, acc);
    else        mlp_layer_acc<400,2>(W3, act, w, t, acc);
    __syncthreads();
    mlp_layer_store(b3, act, w, t, ncc, acc);
    __syncthreads();

    // ---- layer 4: 400 -> 128 (no relu): lane owns col pair (t, 64+t),
    //      wave w rows 4w..4w+3 -- exact R13/R14 mapping/i-order. ----
    float2v a4[4];
    #pragma unroll
    for (int rr = 0; rr < 4; ++rr) a4[rr] = (float2v){0.f, 0.f};
    #pragma unroll 4
    for (int i4 = 0; i4 < 100; ++i4) {
        float wv0[4], wv1[4];
        #pragma unroll
        for (int jj = 0; jj < 4; ++jj) {
            wv0[jj] = W4[(i4*4 + jj)*128 + t];
            wv1[jj] = W4[(i4*4 + jj)*128 + 64 + t];
        }
        #pragma unroll
        for (int rr = 0; rr < 4; ++rr) {
            const float4v xv = *(const float4v*)(act + (w*4 + rr)*AST + i4*4);
            #pragma unroll
            for (int jj = 0; jj < 4; ++jj) {
                a4[rr][0] = fmaf(xv[jj], wv0[jj], a4[rr][0]);
                a4[rr][1] = fmaf(xv[jj], wv1[jj], a4[rr][1]);
            }
        }
    }
    {
        const float b40 = b4[t], b41 = b4[64 + t];
        #pragma unroll
        for (int rr = 0; rr < 4; ++rr) { a4[rr][0] += b40; a4[rr][1] += b41; }
    }
    __syncthreads();                         // all L4 reads of act complete

    // ---- LayerNorm over 128 (2 vals/lane, same 64-lane butterfly) ----
    {
        const float* g  = half ? g_k : g_q;
        const float* be = half ? beta_k : beta_q;
        const float gl0 = g[t],  gl1 = g[64 + t];
        const float bl0 = be[t], bl1 = be[64 + t];
        #pragma unroll
        for (int rr = 0; rr < 4; ++rr) {
            float s = a4[rr][0] + a4[rr][1];
            #pragma unroll
            for (int o = 32; o > 0; o >>= 1) s += __shfl_xor(s, o);
            const float mu = s * (1.f/128.f);
            const float d0 = a4[rr][0] - mu, d1 = a4[rr][1] - mu;
            float vs = d0*d0 + d1*d1;
            #pragma unroll
            for (int o = 32; o > 0; o >>= 1) vs += __shfl_xor(vs, o);
            const float rstd = rsqrtf(vs * (1.f/128.f) + 1e-5f);
            act[(w*4 + rr)*128 + t]      = d0*rstd*gl0 + bl0;
            act[(w*4 + rr)*128 + 64 + t] = d1*rstd*gl1 + bl1;
        }
    }
    __syncthreads();

    // ---- projection 128 -> 512, col-split (all cols real) ----
    {
        const float* Wp = half ? Wk : Wq;
        const float* bp = half ? bk : bq;
        float* of = half ? kf : qf;

        float accp[ROWS][2];
        #pragma unroll
        for (int r = 0; r < ROWS; ++r) { accp[r][0] = 0.f; accp[r][1] = 0.f; }
        #pragma unroll 4
        for (int i4 = 0; i4 < 32; ++i4) {
            float wv[4][2];
            #pragma unroll
            for (int jj = 0; jj < 4; ++jj)
                #pragma unroll
                for (int cc = 0; cc < 2; ++cc)
                    wv[jj][cc] = Wp[(i4*4 + jj)*512 + w*128 + cc*64 + t];
            #pragma unroll
            for (int r = 0; r < ROWS; ++r) {
                const float4v xv = *(const float4v*)(act + r*128 + i4*4);
                #pragma unroll
                for (int jj = 0; jj < 4; ++jj)
                    #pragma unroll
                    for (int cc = 0; cc < 2; ++cc)
                        accp[r][cc] = fmaf(xv[jj], wv[jj][cc], accp[r][cc]);
            }
        }

        float bpv[2];
        bpv[0] = bp[w*128 + t];
        bpv[1] = bp[w*128 + 64 + t];
        #pragma unroll
        for (int r = 0; r < ROWS; ++r) {
            const int gidx = rbase + r;
            const int bb = gidx >> 11, s = gidx & 2047;
            const int T = s >> 4, m16s = s & 15;
            #pragma unroll
            for (int cc = 0; cc < 2; ++cc) {
                const int j  = w*128 + cc*64 + t;
                const int hh = j >> 7, d = j & 127;
                const float v = accp[r][cc] + bpv[cc];
                const size_t dst = ((size_t)(bb*4 + hh)*2048 + s)*128 + d;
                of[dst] = v;
                if (half) {
                    const int ks = d >> 5, qd = (d & 31) >> 3, jj = d & 7;
                    const size_t so = (size_t)(bb*4 + hh)*262144
                                    + (size_t)T*2048 + ks*512 + qd*128 + m16s*8 + jj;
                    khi[so] = __float2bfloat16(v);
                }
            }
        }
    }
}

// ---------------------------------------------------------------------------
// Kernel B: MFMA scan over an m-quarter (512 cols). Per lane: two independent
// sorted depth-12 key lists (2-way ILP); owner (quad0) 8-way tournament merge
// -> top-24 -> wsk. khi fragment-swizzled (contiguous 1KB/wave loads).
// ---------------------------------------------------------------------------
__global__ __launch_bounds__(256, 4) void k_scan(
    const float* __restrict__ qf, const __hip_bfloat16* __restrict__ khi,
    unsigned* __restrict__ wsk)
{
    __shared__ unsigned kd[64*97];     // 24.8KB; row stride 97 (odd) bank-safe

    const int tid   = threadIdx.x;
    const int stile = blockIdx.x;      // 0..31
    const int hb    = blockIdx.y;      // 0..15
    const int mq    = blockIdx.z;      // 0..3

    const int lane = tid & 63;
    const int w    = tid >> 6;
    const int m16  = lane & 15;
    const int quad = lane >> 4;

    const size_t slab = (size_t)hb * 2048;
    const __hip_bfloat16* slabp = khi + (size_t)hb * 262144;   // swizzled slab

    const int sg_my = stile*64 + w*16 + m16;

    // Q fragment (B operand): B[n=m16][k=quad*8+j+ks*32] = q[w*16+n][k]
    short8v bq_[4];
    {
        const float* qp = qf + (slab + sg_my)*128 + quad*8;
        #pragma unroll
        for (int ks = 0; ks < 4; ++ks) {
            const float4 x0 = *(const float4*)(qp + ks*32);
            const float4 x1 = *(const float4*)(qp + ks*32 + 4);
            short8v tt;
            tt[0]=f2bf_s(x0.x); tt[1]=f2bf_s(x0.y); tt[2]=f2bf_s(x0.z); tt[3]=f2bf_s(x0.w);
            tt[4]=f2bf_s(x1.x); tt[5]=f2bf_s(x1.y); tt[6]=f2bf_s(x1.z); tt[7]=f2bf_s(x1.w);
            bq_[ks] = tt;
        }
    }

    unsigned KA[12], KB[12];           // ascending; [0] = min
    #pragma unroll
    for (int n = 0; n < 12; ++n) { KA[n] = 0u; KB[n] = 0u; }

    #pragma unroll 1
    for (int cti = 0; cti < 32; ++cti) {
        const int T = mq*32 + cti;     // global 16-col tile id
        const __hip_bfloat16* kp = slabp + (size_t)T*2048 + lane*8;
        float4v acc = (float4v){0.f,0.f,0.f,0.f};
        #pragma unroll
        for (int ks = 0; ks < 4; ++ks) {
            const short8v ka = *(const short8v*)(kp + ks*512);
            acc = __builtin_amdgcn_mfma_f32_16x16x32_bf16(ka, bq_[ks], acc, 0, 0, 0);
        }
        const int cb = T*16 + quad*4;
        #pragma unroll
        for (int ph = 0; ph < 2; ++ph) {
            {   // KA insert: reg = ph
                const int m = cb + ph;
                unsigned key = (mono(acc[ph]) & 0xFFFFF800u) | (unsigned)m;
                key = (m == sg_my) ? 0u : key;
                KA[0] = umax_(KA[0], key);
                #pragma unroll
                for (int i = 0; i < 11; ++i) {
                    const unsigned a = KA[i], c = KA[i+1];
                    KA[i]   = umin_(a, c);
                    KA[i+1] = umax_(a, c);
                }
            }
            {   // KB insert: reg = 2+ph
                const int m = cb + 2 + ph;
                unsigned key = (mono(acc[2+ph]) & 0xFFFFF800u) | (unsigned)m;
                key = (m == sg_my) ? 0u : key;
                KB[0] = umax_(KB[0], key);
                #pragma unroll
                for (int i = 0; i < 11; ++i) {
                    const unsigned a = KB[i], c = KB[i+1];
                    KB[i]   = umin_(a, c);
                    KB[i+1] = umax_(a, c);
                }
            }
        }
    }

    // dump: per (row, quad) two desc 12-lists
    const int rr = w*16 + m16;
    #pragma unroll
    for (int n = 0; n < 12; ++n) {
        kd[rr*97 + (quad*2 + 0)*12 + n] = KA[11 - n];
        kd[rr*97 + (quad*2 + 1)*12 + n] = KB[11 - n];
    }
    __syncthreads();

    // owner (quad 0): 8-way tournament merge -> top-24 -> ws (desc).
    if (quad == 0) {
        const unsigned* R = &kd[rr*97];
        int q0=0,q1=0,q2=0,q3=0,q4=0,q5=0,q6=0,q7=0;
        const size_t base = (size_t)hb*2048 + stile*64 + rr;
        #pragma unroll 1
        for (int n = 0; n < 24; ++n) {
            const unsigned h0 = (q0<12)?R[  0+q0]:0u;
            const unsigned h1 = (q1<12)?R[ 12+q1]:0u;
            const unsigned h2 = (q2<12)?R[ 24+q2]:0u;
            const unsigned h3 = (q3<12)?R[ 36+q3]:0u;
            const unsigned h4 = (q4<12)?R[ 48+q4]:0u;
            const unsigned h5 = (q5<12)?R[ 60+q5]:0u;
            const unsigned h6 = (q6<12)?R[ 72+q6]:0u;
            const unsigned h7 = (q7<12)?R[ 84+q7]:0u;
            unsigned bv = h0; int bs = 0;
            if (h1 > bv) { bv = h1; bs = 1; }
            if (h2 > bv) { bv = h2; bs = 2; }
            if (h3 > bv) { bv = h3; bs = 3; }
            if (h4 > bv) { bv = h4; bs = 4; }
            if (h5 > bv) { bv = h5; bs = 5; }
            if (h6 > bv) { bv = h6; bs = 6; }
            if (h7 > bv) { bv = h7; bs = 7; }
            q0 += (bs==0); q1 += (bs==1); q2 += (bs==2); q3 += (bs==3);
            q4 += (bs==4); q5 += (bs==5); q6 += (bs==6); q7 += (bs==7);
            wsk[(size_t)(mq*24 + n)*32768 + base] = bv;
        }
    }
}

// ---------------------------------------------------------------------------
// Kernel C: per row merge 4x24 approx keys -> top-32 -> cooperative exact
// fp32 rescore (pk-packed partials) -> exact top-20 -> quantiles + outputs.
// ---------------------------------------------------------------------------
__global__ __launch_bounds__(256, 4) void k_select(
    const float* __restrict__ qf, const float* __restrict__ kf,
    const unsigned* __restrict__ wsk,
    const float* __restrict__ errors, const float* __restrict__ y,
    const float* __restrict__ y_pred,
    float* __restrict__ out, float* __restrict__ hacc)
{
    __shared__ unsigned kd[64*4*25];       // 25.6KB (pad 25)
    __shared__ unsigned short cb[64*33];   // 4.2KB candidate cols
    __shared__ float es[64*33];            // 8.4KB exact scores
    __shared__ float ebuf[64*21];          // 5.4KB sort buffer

    const int tid   = threadIdx.x;
    const int stile = blockIdx.x;          // 0..31
    const int hb    = blockIdx.y;          // 0..15
    const int b     = hb >> 2;
    const int h     = hb & 3;

    const int lane = tid & 63;
    const int w    = tid >> 6;
    const int m16  = lane & 15;
    const int quad = lane >> 4;
    const int rr   = w*16 + m16;
    const int sg   = stile*64 + rr;

    const size_t base = (size_t)hb*2048 + sg;
    #pragma unroll 1
    for (int n = 0; n < 24; ++n)
        kd[(rr*4 + quad)*25 + n] = wsk[(size_t)(quad*24 + n)*32768 + base];
    __syncthreads();

    // owner: merge 4 sorted-desc 24-lists -> approx-top-32 cols
    if (quad == 0) {
        const unsigned* L0 = &kd[(rr*4 + 0)*25];
        const unsigned* L1 = &kd[(rr*4 + 1)*25];
        const unsigned* L2 = &kd[(rr*4 + 2)*25];
        const unsigned* L3 = &kd[(rr*4 + 3)*25];
        int p0 = 0, p1 = 0, p2 = 0, p3 = 0;
        #pragma unroll 1
        for (int n = 0; n < 32; ++n) {
            const unsigned h0 = (p0 < 24) ? L0[p0] : 0u;
            const unsigned h1 = (p1 < 24) ? L1[p1] : 0u;
            const unsigned h2 = (p2 < 24) ? L2[p2] : 0u;
            const unsigned h3 = (p3 < 24) ? L3[p3] : 0u;
            unsigned bv = h0; int bs = 0;
            if (h1 > bv) { bv = h1; bs = 1; }
            if (h2 > bv) { bv = h2; bs = 2; }
            if (h3 > bv) { bv = h3; bs = 3; }
            if (bs == 0) ++p0; else if (bs == 1) ++p1; else if (bs == 2) ++p2; else ++p3;
            cb[rr*33 + n] = (unsigned short)(bv & 0x7FFu);
        }
    }
    __syncthreads();

    // cooperative exact rescore of the 32 candidates (pk-packed partials)
    const size_t slab = (size_t)hb * 2048;
    const float* qrow_p = qf + (slab + sg)*128;
    float4 qseg[8];
    #pragma unroll
    for (int u = 0; u < 8; ++u)
        qseg[u] = *(const float4*)(qrow_p + quad*4 + u*16);
    const float* kslab = kf + slab*128;
    #pragma unroll 1
    for (int n = 0; n < 32; ++n) {
        const int col = cb[rr*33 + n];
        const float* kc = kslab + (size_t)col*128 + quad*4;
        float2v s01 = (float2v){0.f, 0.f}, s23 = (float2v){0.f, 0.f};
        #pragma unroll
        for (int u = 0; u < 8; ++u) {
            const float4 kv = *(const float4*)(kc + u*16);
            s01 = __builtin_elementwise_fma((float2v){qseg[u].x, qseg[u].y},
                                            (float2v){kv.x, kv.y}, s01);
            s23 = __builtin_elementwise_fma((float2v){qseg[u].z, qseg[u].w},
                                            (float2v){kv.z, kv.w}, s23);
        }
        float v = (s01[0] + s01[1]) + (s23[0] + s23[1]);
        v += __shfl_xor(v, 16);
        v += __shfl_xor(v, 32);
        if (quad == 0) es[rr*33 + n] = v;
    }

    // owner: exact top-20 selection (desc, col asc ties) + quantiles
    float sq = 0.f;
    if (quad == 0) {
        float* e = &ebuf[rr*21];
        #pragma unroll 1
        for (int k = 0; k < 20; ++k) {
            float best = -INFINITY; int bc = 4096, bj = 0;
            #pragma unroll 1
            for (int j = 0; j < 32; ++j) {
                const float v = es[rr*33 + j];
                const int c = cb[rr*33 + j];
                if (v > best || (v == best && c < bc)) { best = v; bc = c; bj = j; }
            }
            es[rr*33 + bj] = -INFINITY;
            e[k] = errors[((size_t)(b*SS + bc))*4];   // errors[..., 0]
        }
        #pragma unroll 1
        for (int a = 1; a < 20; ++a) {     // insertion sort ascending
            const float v = e[a];
            int n = a;
            while (n > 0 && e[n-1] > v) { e[n] = e[n-1]; --n; }
            e[n] = v;
        }
        const float yp = y_pred[((size_t)(b*SS + sg))*4];
        const float yt = y[((size_t)(b*SS + sg))*4];
        float msum = 0.f;
        const size_t obase = ((size_t)(h*4 + b)*18)*2048 + sg;
        #pragma unroll 1
        for (int a = 0; a < 18; ++a) {
            const float alpha = c_alphas[a];
            const float beta  = 0.5f*alpha;
            const float pl = beta * 19.f;
            const int   il = (int)pl;
            const float fl = pl - (float)il;
            const float ql = e[il]*(1.f-fl) + e[il+1]*fl;
            const float qq = (1.f - alpha) + beta;
            const float ph = qq * 19.f;
            const int   ih = (int)ph;
            const float fh = ph - (float)ih;
            const float qh = e[ih]*(1.f-fh) + e[ih+1]*fh;
            msum += ql + qh;
            const size_t oidx = obase + (size_t)a*2048;
            out[OFF_YLOW  + oidx] = ql + yp;
            out[OFF_YHIGH + oidx] = qh + yp;
            out[OFF_QLOW  + oidx] = ql;
            out[OFF_QHIGH + oidx] = qh;
        }
        const float me = msum * (1.f/36.f);
        const float dd = yt - (me + yp);
        sq = dd*dd;
    }
    // wave-reduce sq (non-owners contribute 0), one atomic per wave
    #pragma unroll
    for (int o = 32; o > 0; o >>= 1) sq += __shfl_xor(sq, o);
    if (lane == 0) atomicAdd(&hacc[h], sq);
}

__global__ void k_init(float* __restrict__ hacc) {
    if (threadIdx.x < 4) hacc[threadIdx.x] = 0.f;
}

__global__ __launch_bounds__(256) void k_finalize(
    const float* __restrict__ y, const float* __restrict__ y_pred,
    const float* __restrict__ errors, const float* __restrict__ hacc,
    float* __restrict__ out)
{
    const int i = blockIdx.x*256 + threadIdx.x;
    if (i == 0)
        out[0] = (hacc[0]+hacc[1]+hacc[2]+hacc[3]) * (1.f/32768.f);
    if (i < 32768)      out[OFF_Y + i] = y[i];
    else if (i < 65536) out[OFF_YPRED + (i - 32768)] = y_pred[i - 32768];
    else if (i < 73728) { const int j = i - 65536; out[OFF_ERR + j] = errors[(size_t)j*4]; }
}

extern "C" void kernel_launch(void* const* d_in, const int* in_sizes, int n_in,
                              void* d_out, int out_size, void* d_ws, size_t ws_size,
                              hipStream_t stream)
{
    const float* Xt     = (const float*)d_in[0];
    const float* Xs     = (const float*)d_in[1];
    const float* errors = (const float*)d_in[2];
    const float* y      = (const float*)d_in[3];
    const float* y_pred = (const float*)d_in[4];
    const float* W1 = (const float*)d_in[5];   const float* b1 = (const float*)d_in[6];
    const float* W2 = (const float*)d_in[7];   const float* b2 = (const float*)d_in[8];
    const float* W3 = (const float*)d_in[9];   const float* b3 = (const float*)d_in[10];
    const float* W4 = (const float*)d_in[11];  const float* b4 = (const float*)d_in[12];
    const float* Wq = (const float*)d_in[13];  const float* bq = (const float*)d_in[14];
    const float* Wk = (const float*)d_in[15];  const float* bk = (const float*)d_in[16];
    const float* g_q    = (const float*)d_in[17];
    const float* beta_q = (const float*)d_in[18];
    const float* g_k    = (const float*)d_in[19];
    const float* beta_k = (const float*)d_in[20];

    float* out  = (float*)d_out;
    char*  base = (char*)d_ws;
    const size_t SLAB = (size_t)16*2048*128;               // 4,194,304 elements
    float* hacc = (float*)base;                            // 64B slot
    float* qf   = (float*)(base + 256);                    // 16MB
    float* kf   = qf + SLAB;                               // 16MB
    __hip_bfloat16* khi = (__hip_bfloat16*)(kf + SLAB);    // 8MB (swizzled)
    unsigned* wsk = (unsigned*)(khi + SLAB);               // 12.6MB

    k_init<<<1, 64, 0, stream>>>(hacc);
    k_mlp<<<1024, 256, 0, stream>>>(Xt, Xs, W1,b1,W2,b2,W3,b3,W4,b4,
                                    Wq,bq,Wk,bk,g_q,beta_q,g_k,beta_k,
                                    qf, kf, khi);
    k_scan<<<dim3(32,16,4), 256, 0, stream>>>(qf, khi, wsk);
    k_select<<<dim3(32,16), 256, 0, stream>>>(qf, kf, wsk, errors, y, y_pred, out, hacc);
    k_finalize<<<288, 256, 0, stream>>>(y, y_pred, errors, hacc, out);
}

// Round 10
// 618.419 us; speedup vs baseline: 1.1445x; 1.0206x over previous
//
#include <hip/hip_runtime.h>
#include <hip/hip_bf16.h>
#include <math.h>

// ConformHopfieldBatch: B=4 S=2048 IN=64 D=128 HID=400 H=4 K=20 NQ=18
// softmax monotone -> top_k(assoc) == top_k(raw scores). bf16-hi MFMA
// PREFILTER -> approx candidates; exact fp32 RESCORE -> true top-20 (R2).
// Session law (R13..R21): k_mlp tracks VGPR headroom+schedule quality, not
// occupancy/op-count. R14 (VGPR64, unroll2) = 278us BEST. R21 (unroll4):
// compiler KEPT VGPR=64 (refused deeper buffering) and regressed to 330.
// Model: one K-step of weight loads in flight; each step ends on a
// vmcnt/lgkmcnt wait (~200cyc L2) that 4 waves/SIMD partly cover (42% duty).
// R22: R14 source + MANUAL 2-stage software pipeline of the WEIGHT LOADS
// in the 5 GEMM loops (L1/L2/L3, L4, proj): named cur/next buffers force
// next-step loads above the FMA block. Loads are pure reads; per-column
// FMA order untouched -> outputs bit-identical. k_scan/k_select/k_finalize
// byte-identical to R14.

#define SS 2048
#define ROWS 16
#define AST 400   // LDS activation row stride (floats); 1600B, 16B-aligned

typedef short short8v __attribute__((ext_vector_type(8)));
typedef float float4v __attribute__((ext_vector_type(4)));
typedef float float2v __attribute__((ext_vector_type(2)));

__constant__ float c_alphas[18] = {0.05f,0.06f,0.08f,0.1f,0.12f,0.14f,0.15f,0.17f,
                                   0.19f,0.2f,0.21f,0.23f,0.25f,0.3f,0.35f,0.38f,0.4f,0.45f};

// output flat offsets (return-order concat)
#define OFF_Y      1
#define OFF_YPRED  32769
#define OFF_YLOW   65537ll
#define OFF_YHIGH  655361ll
#define OFF_ERR    1245185ll
#define OFF_QLOW   1253377ll
#define OFF_QHIGH  1843201ll

__device__ inline short f2bf_s(float f) {
    __hip_bfloat16 h = __float2bfloat16(f);
    return __builtin_bit_cast(short, h);
}
// monotone fp32 -> u32 map (order-preserving)
__device__ inline unsigned mono(float f) {
    unsigned u = __builtin_bit_cast(unsigned, f);
    return (u & 0x80000000u) ? ~u : (u | 0x80000000u);
}
__device__ inline unsigned umin_(unsigned a, unsigned b) { return a < b ? a : b; }
__device__ inline unsigned umax_(unsigned a, unsigned b) { return a > b ? a : b; }

// ---------------------------------------------------------------------------
// Kernel A: fused MLP + LayerNorm + projection. 256 threads (4 waves),
// 16 rows/block, grid 1024. Activations in LDS; x broadcast via uniform
// ds_read_b128; weights streamed coalesced with a MANUAL 2-stage prefetch
// pipeline (cur/next register buffers). Column-split across waves for
// 400/512-wide layers; row-split for L4+LN. Per-column FMA order identical
// to R12..R14 -> bit-identical outputs.
// ---------------------------------------------------------------------------

template<int IN_W, int NCC>
__device__ __forceinline__ void mlp_layer_acc(
    const float* __restrict__ W, const float* __restrict__ act,
    const int w, const int t, float (&acc)[ROWS][2])
{
    int jm[2];
    #pragma unroll
    for (int cc = 0; cc < NCC; ++cc) {
        const int j = w*128 + cc*64 + t;
        jm[cc] = (j < 400) ? j : 399;      // clamped dummy (discarded at store)
    }
    #pragma unroll
    for (int r = 0; r < ROWS; ++r)
        #pragma unroll
        for (int cc = 0; cc < NCC; ++cc) acc[r][cc] = 0.f;

    constexpr int NI = IN_W/4;
    float wv[4][2];                        // current-step weights
    #pragma unroll
    for (int jj = 0; jj < 4; ++jj)
        #pragma unroll
        for (int cc = 0; cc < NCC; ++cc)
            wv[jj][cc] = W[jj*400 + jm[cc]];

    #pragma unroll 2
    for (int i4 = 0; i4 < NI - 1; ++i4) {
        float wn[4][2];                    // next-step prefetch (issued early)
        #pragma unroll
        for (int jj = 0; jj < 4; ++jj)
            #pragma unroll
            for (int cc = 0; cc < NCC; ++cc)
                wn[jj][cc] = W[((i4+1)*4 + jj)*400 + jm[cc]];
        #pragma unroll
        for (int r = 0; r < ROWS; ++r) {
            const float4v xv = *(const float4v*)(act + r*AST + i4*4);
            #pragma unroll
            for (int jj = 0; jj < 4; ++jj)
                #pragma unroll
                for (int cc = 0; cc < NCC; ++cc)
                    acc[r][cc] = fmaf(xv[jj], wv[jj][cc], acc[r][cc]);
        }
        #pragma unroll
        for (int jj = 0; jj < 4; ++jj)
            #pragma unroll
            for (int cc = 0; cc < NCC; ++cc)
                wv[jj][cc] = wn[jj][cc];
    }
    {   // epilogue step NI-1
        #pragma unroll
        for (int r = 0; r < ROWS; ++r) {
            const float4v xv = *(const float4v*)(act + r*AST + (NI-1)*4);
            #pragma unroll
            for (int jj = 0; jj < 4; ++jj)
                #pragma unroll
                for (int cc = 0; cc < NCC; ++cc)
                    acc[r][cc] = fmaf(xv[jj], wv[jj][cc], acc[r][cc]);
        }
    }
}

__device__ __forceinline__ void mlp_layer_store(
    const float* __restrict__ b, float* __restrict__ act,
    const int w, const int t, const int ncc, const float (&acc)[ROWS][2])
{
    #pragma unroll
    for (int cc = 0; cc < 2; ++cc) {          // static cc -> no scratch
        const int j = w*128 + cc*64 + t;
        if (cc < ncc && j < 400) {
            const float bv = b[j];
            #pragma unroll
            for (int r = 0; r < ROWS; ++r)
                act[r*AST + j] = fmaxf(acc[r][cc] + bv, 0.f);
        }
    }
}

__global__ __launch_bounds__(256, 4) void k_mlp(
    const float* __restrict__ Xt, const float* __restrict__ Xs,
    const float* __restrict__ W1, const float* __restrict__ b1,
    const float* __restrict__ W2, const float* __restrict__ b2,
    const float* __restrict__ W3, const float* __restrict__ b3,
    const float* __restrict__ W4, const float* __restrict__ b4,
    const float* __restrict__ Wq, const float* __restrict__ bq,
    const float* __restrict__ Wk, const float* __restrict__ bk,
    const float* __restrict__ g_q, const float* __restrict__ beta_q,
    const float* __restrict__ g_k, const float* __restrict__ beta_k,
    float* __restrict__ qf, float* __restrict__ kf,
    __hip_bfloat16* __restrict__ khi)
{
    __shared__ float act[ROWS*AST];          // 25.6 KB

    const int tid  = threadIdx.x;
    const int t    = tid & 63;
    const int w    = tid >> 6;               // wave 0..3
    const int bi   = blockIdx.x;
    const int half = bi >> 9;                // 0:true/q 1:sim/k
    const int rbase = (bi & 511) * ROWS;
    const float* X = half ? Xs : Xt;

    // stage input rows (16 x 64, coalesced)
    #pragma unroll
    for (int u = 0; u < (ROWS*64)/256; ++u) {
        const int e = u*256 + tid;
        act[(e >> 6)*AST + (e & 63)] = X[(size_t)rbase*64 + e];
    }
    __syncthreads();

    float acc[ROWS][2];
    const int ncc = (w == 3) ? 1 : 2;        // wave3: cols 448..511 all dummy

    // ---- layer 1: 64 -> 400 (relu) ----
    if (w == 3) mlp_layer_acc<64,1>(W1, act, w, t, acc);
    else        mlp_layer_acc<64,2>(W1, act, w, t, acc);
    __syncthreads();
    mlp_layer_store(b1, act, w, t, ncc, acc);
    __syncthreads();

    // ---- layer 2: 400 -> 400 (relu) ----
    if (w == 3) mlp_layer_acc<400,1>(W2, act, w, t, acc);
    else        mlp_layer_acc<400,2>(W2, act, w, t, acc);
    __syncthreads();
    mlp_layer_store(b2, act, w, t, ncc, acc);
    __syncthreads();

    // ---- layer 3: 400 -> 400 (relu) ----
    if (w == 3) mlp_layer_acc<400,1>(W3, act, w, t, acc);
    else        mlp_layer_acc<400,2>(W3, act, w, t, acc);
    __syncthreads();
    mlp_layer_store(b3, act, w, t, ncc, acc);
    __syncthreads();

    // ---- layer 4: 400 -> 128 (no relu): lane owns col pair (t, 64+t),
    //      wave w rows 4w..4w+3 -- exact R13/R14 mapping/i-order;
    //      manual 2-stage weight prefetch. ----
    float2v a4[4];
    #pragma unroll
    for (int rr = 0; rr < 4; ++rr) a4[rr] = (float2v){0.f, 0.f};
    {
        float wv0[4], wv1[4];
        #pragma unroll
        for (int jj = 0; jj < 4; ++jj) {
            wv0[jj] = W4[jj*128 + t];
            wv1[jj] = W4[jj*128 + 64 + t];
        }
        #pragma unroll 2
        for (int i4 = 0; i4 < 99; ++i4) {
            float wn0[4], wn1[4];
            #pragma unroll
            for (int jj = 0; jj < 4; ++jj) {
                wn0[jj] = W4[((i4+1)*4 + jj)*128 + t];
                wn1[jj] = W4[((i4+1)*4 + jj)*128 + 64 + t];
            }
            #pragma unroll
            for (int rr = 0; rr < 4; ++rr) {
                const float4v xv = *(const float4v*)(act + (w*4 + rr)*AST + i4*4);
                #pragma unroll
                for (int jj = 0; jj < 4; ++jj) {
                    a4[rr][0] = fmaf(xv[jj], wv0[jj], a4[rr][0]);
                    a4[rr][1] = fmaf(xv[jj], wv1[jj], a4[rr][1]);
                }
            }
            #pragma unroll
            for (int jj = 0; jj < 4; ++jj) { wv0[jj] = wn0[jj]; wv1[jj] = wn1[jj]; }
        }
        #pragma unroll
        for (int rr = 0; rr < 4; ++rr) {
            const float4v xv = *(const float4v*)(act + (w*4 + rr)*AST + 99*4);
            #pragma unroll
            for (int jj = 0; jj < 4; ++jj) {
                a4[rr][0] = fmaf(xv[jj], wv0[jj], a4[rr][0]);
                a4[rr][1] = fmaf(xv[jj], wv1[jj], a4[rr][1]);
            }
        }
    }
    {
        const float b40 = b4[t], b41 = b4[64 + t];
        #pragma unroll
        for (int rr = 0; rr < 4; ++rr) { a4[rr][0] += b40; a4[rr][1] += b41; }
    }
    __syncthreads();                         // all L4 reads of act complete

    // ---- LayerNorm over 128 (2 vals/lane, same 64-lane butterfly) ----
    {
        const float* g  = half ? g_k : g_q;
        const float* be = half ? beta_k : beta_q;
        const float gl0 = g[t],  gl1 = g[64 + t];
        const float bl0 = be[t], bl1 = be[64 + t];
        #pragma unroll
        for (int rr = 0; rr < 4; ++rr) {
            float s = a4[rr][0] + a4[rr][1];
            #pragma unroll
            for (int o = 32; o > 0; o >>= 1) s += __shfl_xor(s, o);
            const float mu = s * (1.f/128.f);
            const float d0 = a4[rr][0] - mu, d1 = a4[rr][1] - mu;
            float vs = d0*d0 + d1*d1;
            #pragma unroll
            for (int o = 32; o > 0; o >>= 1) vs += __shfl_xor(vs, o);
            const float rstd = rsqrtf(vs * (1.f/128.f) + 1e-5f);
            act[(w*4 + rr)*128 + t]      = d0*rstd*gl0 + bl0;
            act[(w*4 + rr)*128 + 64 + t] = d1*rstd*gl1 + bl1;
        }
    }
    __syncthreads();

    // ---- projection 128 -> 512, col-split (all cols real);
    //      manual 2-stage weight prefetch. ----
    {
        const float* Wp = half ? Wk : Wq;
        const float* bp = half ? bk : bq;
        float* of = half ? kf : qf;

        float accp[ROWS][2];
        #pragma unroll
        for (int r = 0; r < ROWS; ++r) { accp[r][0] = 0.f; accp[r][1] = 0.f; }

        float wv[4][2];
        #pragma unroll
        for (int jj = 0; jj < 4; ++jj)
            #pragma unroll
            for (int cc = 0; cc < 2; ++cc)
                wv[jj][cc] = Wp[jj*512 + w*128 + cc*64 + t];

        #pragma unroll 2
        for (int i4 = 0; i4 < 31; ++i4) {
            float wn[4][2];
            #pragma unroll
            for (int jj = 0; jj < 4; ++jj)
                #pragma unroll
                for (int cc = 0; cc < 2; ++cc)
                    wn[jj][cc] = Wp[((i4+1)*4 + jj)*512 + w*128 + cc*64 + t];
            #pragma unroll
            for (int r = 0; r < ROWS; ++r) {
                const float4v xv = *(const float4v*)(act + r*128 + i4*4);
                #pragma unroll
                for (int jj = 0; jj < 4; ++jj)
                    #pragma unroll
                    for (int cc = 0; cc < 2; ++cc)
                        accp[r][cc] = fmaf(xv[jj], wv[jj][cc], accp[r][cc]);
            }
            #pragma unroll
            for (int jj = 0; jj < 4; ++jj)
                #pragma unroll
                for (int cc = 0; cc < 2; ++cc)
                    wv[jj][cc] = wn[jj][cc];
        }
        #pragma unroll
        for (int r = 0; r < ROWS; ++r) {
            const float4v xv = *(const float4v*)(act + r*128 + 31*4);
            #pragma unroll
            for (int jj = 0; jj < 4; ++jj)
                #pragma unroll
                for (int cc = 0; cc < 2; ++cc)
                    accp[r][cc] = fmaf(xv[jj], wv[jj][cc], accp[r][cc]);
        }

        float bpv[2];
        bpv[0] = bp[w*128 + t];
        bpv[1] = bp[w*128 + 64 + t];
        #pragma unroll
        for (int r = 0; r < ROWS; ++r) {
            const int gidx = rbase + r;
            const int bb = gidx >> 11, s = gidx & 2047;
            const int T = s >> 4, m16s = s & 15;
            #pragma unroll
            for (int cc = 0; cc < 2; ++cc) {
                const int j  = w*128 + cc*64 + t;
                const int hh = j >> 7, d = j & 127;
                const float v = accp[r][cc] + bpv[cc];
                const size_t dst = ((size_t)(bb*4 + hh)*2048 + s)*128 + d;
                of[dst] = v;
                if (half) {
                    const int ks = d >> 5, qd = (d & 31) >> 3, jj = d & 7;
                    const size_t so = (size_t)(bb*4 + hh)*262144
                                    + (size_t)T*2048 + ks*512 + qd*128 + m16s*8 + jj;
                    khi[so] = __float2bfloat16(v);
                }
            }
        }
    }
}

// ---------------------------------------------------------------------------
// Kernel B: MFMA scan over an m-quarter (512 cols). Per lane: two independent
// sorted depth-12 key lists (2-way ILP); owner (quad0) 8-way tournament merge
// -> top-24 -> wsk. khi fragment-swizzled (contiguous 1KB/wave loads).
// ---------------------------------------------------------------------------
__global__ __launch_bounds__(256, 4) void k_scan(
    const float* __restrict__ qf, const __hip_bfloat16* __restrict__ khi,
    unsigned* __restrict__ wsk)
{
    __shared__ unsigned kd[64*97];     // 24.8KB; row stride 97 (odd) bank-safe

    const int tid   = threadIdx.x;
    const int stile = blockIdx.x;      // 0..31
    const int hb    = blockIdx.y;      // 0..15
    const int mq    = blockIdx.z;      // 0..3

    const int lane = tid & 63;
    const int w    = tid >> 6;
    const int m16  = lane & 15;
    const int quad = lane >> 4;

    const size_t slab = (size_t)hb * 2048;
    const __hip_bfloat16* slabp = khi + (size_t)hb * 262144;   // swizzled slab

    const int sg_my = stile*64 + w*16 + m16;

    // Q fragment (B operand): B[n=m16][k=quad*8+j+ks*32] = q[w*16+n][k]
    short8v bq_[4];
    {
        const float* qp = qf + (slab + sg_my)*128 + quad*8;
        #pragma unroll
        for (int ks = 0; ks < 4; ++ks) {
            const float4 x0 = *(const float4*)(qp + ks*32);
            const float4 x1 = *(const float4*)(qp + ks*32 + 4);
            short8v tt;
            tt[0]=f2bf_s(x0.x); tt[1]=f2bf_s(x0.y); tt[2]=f2bf_s(x0.z); tt[3]=f2bf_s(x0.w);
            tt[4]=f2bf_s(x1.x); tt[5]=f2bf_s(x1.y); tt[6]=f2bf_s(x1.z); tt[7]=f2bf_s(x1.w);
            bq_[ks] = tt;
        }
    }

    unsigned KA[12], KB[12];           // ascending; [0] = min
    #pragma unroll
    for (int n = 0; n < 12; ++n) { KA[n] = 0u; KB[n] = 0u; }

    #pragma unroll 1
    for (int cti = 0; cti < 32; ++cti) {
        const int T = mq*32 + cti;     // global 16-col tile id
        const __hip_bfloat16* kp = slabp + (size_t)T*2048 + lane*8;
        float4v acc = (float4v){0.f,0.f,0.f,0.f};
        #pragma unroll
        for (int ks = 0; ks < 4; ++ks) {
            const short8v ka = *(const short8v*)(kp + ks*512);
            acc = __builtin_amdgcn_mfma_f32_16x16x32_bf16(ka, bq_[ks], acc, 0, 0, 0);
        }
        const int cb = T*16 + quad*4;
        #pragma unroll
        for (int ph = 0; ph < 2; ++ph) {
            {   // KA insert: reg = ph
                const int m = cb + ph;
                unsigned key = (mono(acc[ph]) & 0xFFFFF800u) | (unsigned)m;
                key = (m == sg_my) ? 0u : key;
                KA[0] = umax_(KA[0], key);
                #pragma unroll
                for (int i = 0; i < 11; ++i) {
                    const unsigned a = KA[i], c = KA[i+1];
                    KA[i]   = umin_(a, c);
                    KA[i+1] = umax_(a, c);
                }
            }
            {   // KB insert: reg = 2+ph
                const int m = cb + 2 + ph;
                unsigned key = (mono(acc[2+ph]) & 0xFFFFF800u) | (unsigned)m;
                key = (m == sg_my) ? 0u : key;
                KB[0] = umax_(KB[0], key);
                #pragma unroll
                for (int i = 0; i < 11; ++i) {
                    const unsigned a = KB[i], c = KB[i+1];
                    KB[i]   = umin_(a, c);
                    KB[i+1] = umax_(a, c);
                }
            }
        }
    }

    // dump: per (row, quad) two desc 12-lists
    const int rr = w*16 + m16;
    #pragma unroll
    for (int n = 0; n < 12; ++n) {
        kd[rr*97 + (quad*2 + 0)*12 + n] = KA[11 - n];
        kd[rr*97 + (quad*2 + 1)*12 + n] = KB[11 - n];
    }
    __syncthreads();

    // owner (quad 0): 8-way tournament merge -> top-24 -> ws (desc).
    if (quad == 0) {
        const unsigned* R = &kd[rr*97];
        int q0=0,q1=0,q2=0,q3=0,q4=0,q5=0,q6=0,q7=0;
        const size_t base = (size_t)hb*2048 + stile*64 + rr;
        #pragma unroll 1
        for (int n = 0; n < 24; ++n) {
            const unsigned h0 = (q0<12)?R[  0+q0]:0u;
            const unsigned h1 = (q1<12)?R[ 12+q1]:0u;
            const unsigned h2 = (q2<12)?R[ 24+q2]:0u;
            const unsigned h3 = (q3<12)?R[ 36+q3]:0u;
            const unsigned h4 = (q4<12)?R[ 48+q4]:0u;
            const unsigned h5 = (q5<12)?R[ 60+q5]:0u;
            const unsigned h6 = (q6<12)?R[ 72+q6]:0u;
            const unsigned h7 = (q7<12)?R[ 84+q7]:0u;
            unsigned bv = h0; int bs = 0;
            if (h1 > bv) { bv = h1; bs = 1; }
            if (h2 > bv) { bv = h2; bs = 2; }
            if (h3 > bv) { bv = h3; bs = 3; }
            if (h4 > bv) { bv = h4; bs = 4; }
            if (h5 > bv) { bv = h5; bs = 5; }
            if (h6 > bv) { bv = h6; bs = 6; }
            if (h7 > bv) { bv = h7; bs = 7; }
            q0 += (bs==0); q1 += (bs==1); q2 += (bs==2); q3 += (bs==3);
            q4 += (bs==4); q5 += (bs==5); q6 += (bs==6); q7 += (bs==7);
            wsk[(size_t)(mq*24 + n)*32768 + base] = bv;
        }
    }
}

// ---------------------------------------------------------------------------
// Kernel C: per row merge 4x24 approx keys -> top-32 -> cooperative exact
// fp32 rescore (pk-packed partials) -> exact top-20 -> quantiles + outputs.
// ---------------------------------------------------------------------------
__global__ __launch_bounds__(256, 4) void k_select(
    const float* __restrict__ qf, const float* __restrict__ kf,
    const unsigned* __restrict__ wsk,
    const float* __restrict__ errors, const float* __restrict__ y,
    const float* __restrict__ y_pred,
    float* __restrict__ out, float* __restrict__ hacc)
{
    __shared__ unsigned kd[64*4*25];       // 25.6KB (pad 25)
    __shared__ unsigned short cb[64*33];   // 4.2KB candidate cols
    __shared__ float es[64*33];            // 8.4KB exact scores
    __shared__ float ebuf[64*21];          // 5.4KB sort buffer

    const int tid   = threadIdx.x;
    const int stile = blockIdx.x;          // 0..31
    const int hb    = blockIdx.y;          // 0..15
    const int b     = hb >> 2;
    const int h     = hb & 3;

    const int lane = tid & 63;
    const int w    = tid >> 6;
    const int m16  = lane & 15;
    const int quad = lane >> 4;
    const int rr   = w*16 + m16;
    const int sg   = stile*64 + rr;

    const size_t base = (size_t)hb*2048 + sg;
    #pragma unroll 1
    for (int n = 0; n < 24; ++n)
        kd[(rr*4 + quad)*25 + n] = wsk[(size_t)(quad*24 + n)*32768 + base];
    __syncthreads();

    // owner: merge 4 sorted-desc 24-lists -> approx-top-32 cols
    if (quad == 0) {
        const unsigned* L0 = &kd[(rr*4 + 0)*25];
        const unsigned* L1 = &kd[(rr*4 + 1)*25];
        const unsigned* L2 = &kd[(rr*4 + 2)*25];
        const unsigned* L3 = &kd[(rr*4 + 3)*25];
        int p0 = 0, p1 = 0, p2 = 0, p3 = 0;
        #pragma unroll 1
        for (int n = 0; n < 32; ++n) {
            const unsigned h0 = (p0 < 24) ? L0[p0] : 0u;
            const unsigned h1 = (p1 < 24) ? L1[p1] : 0u;
            const unsigned h2 = (p2 < 24) ? L2[p2] : 0u;
            const unsigned h3 = (p3 < 24) ? L3[p3] : 0u;
            unsigned bv = h0; int bs = 0;
            if (h1 > bv) { bv = h1; bs = 1; }
            if (h2 > bv) { bv = h2; bs = 2; }
            if (h3 > bv) { bv = h3; bs = 3; }
            if (bs == 0) ++p0; else if (bs == 1) ++p1; else if (bs == 2) ++p2; else ++p3;
            cb[rr*33 + n] = (unsigned short)(bv & 0x7FFu);
        }
    }
    __syncthreads();

    // cooperative exact rescore of the 32 candidates (pk-packed partials)
    const size_t slab = (size_t)hb * 2048;
    const float* qrow_p = qf + (slab + sg)*128;
    float4 qseg[8];
    #pragma unroll
    for (int u = 0; u < 8; ++u)
        qseg[u] = *(const float4*)(qrow_p + quad*4 + u*16);
    const float* kslab = kf + slab*128;
    #pragma unroll 1
    for (int n = 0; n < 32; ++n) {
        const int col = cb[rr*33 + n];
        const float* kc = kslab + (size_t)col*128 + quad*4;
        float2v s01 = (float2v){0.f, 0.f}, s23 = (float2v){0.f, 0.f};
        #pragma unroll
        for (int u = 0; u < 8; ++u) {
            const float4 kv = *(const float4*)(kc + u*16);
            s01 = __builtin_elementwise_fma((float2v){qseg[u].x, qseg[u].y},
                                            (float2v){kv.x, kv.y}, s01);
            s23 = __builtin_elementwise_fma((float2v){qseg[u].z, qseg[u].w},
                                            (float2v){kv.z, kv.w}, s23);
        }
        float v = (s01[0] + s01[1]) + (s23[0] + s23[1]);
        v += __shfl_xor(v, 16);
        v += __shfl_xor(v, 32);
        if (quad == 0) es[rr*33 + n] = v;
    }

    // owner: exact top-20 selection (desc, col asc ties) + quantiles
    float sq = 0.f;
    if (quad == 0) {
        float* e = &ebuf[rr*21];
        #pragma unroll 1
        for (int k = 0; k < 20; ++k) {
            float best = -INFINITY; int bc = 4096, bj = 0;
            #pragma unroll 1
            for (int j = 0; j < 32; ++j) {
                const float v = es[rr*33 + j];
                const int c = cb[rr*33 + j];
                if (v > best || (v == best && c < bc)) { best = v; bc = c; bj = j; }
            }
            es[rr*33 + bj] = -INFINITY;
            e[k] = errors[((size_t)(b*SS + bc))*4];   // errors[..., 0]
        }
        #pragma unroll 1
        for (int a = 1; a < 20; ++a) {     // insertion sort ascending
            const float v = e[a];
            int n = a;
            while (n > 0 && e[n-1] > v) { e[n] = e[n-1]; --n; }
            e[n] = v;
        }
        const float yp = y_pred[((size_t)(b*SS + sg))*4];
        const float yt = y[((size_t)(b*SS + sg))*4];
        float msum = 0.f;
        const size_t obase = ((size_t)(h*4 + b)*18)*2048 + sg;
        #pragma unroll 1
        for (int a = 0; a < 18; ++a) {
            const float alpha = c_alphas[a];
            const float beta  = 0.5f*alpha;
            const float pl = beta * 19.f;
            const int   il = (int)pl;
            const float fl = pl - (float)il;
            const float ql = e[il]*(1.f-fl) + e[il+1]*fl;
            const float qq = (1.f - alpha) + beta;
            const float ph = qq * 19.f;
            const int   ih = (int)ph;
            const float fh = ph - (float)ih;
            const float qh = e[ih]*(1.f-fh) + e[ih+1]*fh;
            msum += ql + qh;
            const size_t oidx = obase + (size_t)a*2048;
            out[OFF_YLOW  + oidx] = ql + yp;
            out[OFF_YHIGH + oidx] = qh + yp;
            out[OFF_QLOW  + oidx] = ql;
            out[OFF_QHIGH + oidx] = qh;
        }
        const float me = msum * (1.f/36.f);
        const float dd = yt - (me + yp);
        sq = dd*dd;
    }
    // wave-reduce sq (non-owners contribute 0), one atomic per wave
    #pragma unroll
    for (int o = 32; o > 0; o >>= 1) sq += __shfl_xor(sq, o);
    if (lane == 0) atomicAdd(&hacc[h], sq);
}

__global__ void k_init(float* __restrict__ hacc) {
    if (threadIdx.x < 4) hacc[threadIdx.x] = 0.f;
}

__global__ __launch_bounds__(256) void k_finalize(
    const float* __restrict__ y, const float* __restrict__ y_pred,
    const float* __restrict__ errors, const float* __restrict__ hacc,
    float* __restrict__ out)
{
    const int i = blockIdx.x*256 + threadIdx.x;
    if (i == 0)
        out[0] = (hacc[0]+hacc[1]+hacc[2]+hacc[3]) * (1.f/32768.f);
    if (i < 32768)      out[OFF_Y + i] = y[i];
    else if (i < 65536) out[OFF_YPRED + (i - 32768)] = y_pred[i - 32768];
    else if (i < 73728) { const int j = i - 65536; out[OFF_ERR + j] = errors[(size_t)j*4]; }
}

extern "C" void kernel_launch(void* const* d_in, const int* in_sizes, int n_in,
                              void* d_out, int out_size, void* d_ws, size_t ws_size,
                              hipStream_t stream)
{
    const float* Xt     = (const float*)d_in[0];
    const float* Xs     = (const float*)d_in[1];
    const float* errors = (const float*)d_in[2];
    const float* y      = (const float*)d_in[3];
    const float* y_pred = (const float*)d_in[4];
    const float* W1 = (const float*)d_in[5];   const float* b1 = (const float*)d_in[6];
    const float* W2 = (const float*)d_in[7];   const float* b2 = (const float*)d_in[8];
    const float* W3 = (const float*)d_in[9];   const float* b3 = (const float*)d_in[10];
    const float* W4 = (const float*)d_in[11];  const float* b4 = (const float*)d_in[12];
    const float* Wq = (const float*)d_in[13];  const float* bq = (const float*)d_in[14];
    const float* Wk = (const float*)d_in[15];  const float* bk = (const float*)d_in[16];
    const float* g_q    = (const float*)d_in[17];
    const float* beta_q = (const float*)d_in[18];
    const float* g_k    = (const float*)d_in[19];
    const float* beta_k = (const float*)d_in[20];

    float* out  = (float*)d_out;
    char*  base = (char*)d_ws;
    const size_t SLAB = (size_t)16*2048*128;               // 4,194,304 elements
    float* hacc = (float*)base;                            // 64B slot
    float* qf   = (float*)(base + 256);                    // 16MB
    float* kf   = qf + SLAB;                               // 16MB
    __hip_bfloat16* khi = (__hip_bfloat16*)(kf + SLAB);    // 8MB (swizzled)
    unsigned* wsk = (unsigned*)(khi + SLAB);               // 12.6MB

    k_init<<<1, 64, 0, stream>>>(hacc);
    k_mlp<<<1024, 256, 0, stream>>>(Xt, Xs, W1,b1,W2,b2,W3,b3,W4,b4,
                                    Wq,bq,Wk,bk,g_q,beta_q,g_k,beta_k,
                                    qf, kf, khi);
    k_scan<<<dim3(32,16,4), 256, 0, stream>>>(qf, khi, wsk);
    k_select<<<dim3(32,16), 256, 0, stream>>>(qf, kf, wsk, errors, y, y_pred, out, hacc);
    k_finalize<<<288, 256, 0, stream>>>(y, y_pred, errors, hacc, out);
}

// Round 11
// 601.799 us; speedup vs baseline: 1.1761x; 1.0276x over previous
//
#include <hip/hip_runtime.h>
#include <hip/hip_bf16.h>
#include <math.h>

// ConformHopfieldBatch: B=4 S=2048 IN=64 D=128 HID=400 H=4 K=20 NQ=18
// softmax monotone -> top_k(assoc) == top_k(raw scores). bf16-hi MFMA
// PREFILTER -> approx candidates; exact fp32 RESCORE -> true top-20 (R2).
// Session law (R13..R22): k_mlp = 278us is the practical floor of the VALU
// formulation -- 8 structural variants (occupancy up, op-count down,
// ds_read down, unroll, manual prefetch) all <= R14. k_mlp FROZEN at R14.
// R23: attack the unprofiled ~330us pool (k_scan+k_select) with pure
// pipeline pragmas: (1) k_scan cti loop unroll 1->2 -- iter i+1's
// loads+MFMA (matrix pipe) independent of iter i's inserts (VALU pipe,
// KA/KB carried) -> pipes overlap instead of alternating. (2) k_select
// rescore unroll 1->2 -- two independent column-dots in flight at the
// kernel's 2-waves/SIMD occupancy. (3) k_select wsk loads unroll 1->4.
// No FMA/insert/compare reorder within any chain -> outputs bit-identical.

#define SS 2048
#define ROWS 16
#define AST 400   // LDS activation row stride (floats); 1600B, 16B-aligned

typedef short short8v __attribute__((ext_vector_type(8)));
typedef float float4v __attribute__((ext_vector_type(4)));
typedef float float2v __attribute__((ext_vector_type(2)));

__constant__ float c_alphas[18] = {0.05f,0.06f,0.08f,0.1f,0.12f,0.14f,0.15f,0.17f,
                                   0.19f,0.2f,0.21f,0.23f,0.25f,0.3f,0.35f,0.38f,0.4f,0.45f};

// output flat offsets (return-order concat)
#define OFF_Y      1
#define OFF_YPRED  32769
#define OFF_YLOW   65537ll
#define OFF_YHIGH  655361ll
#define OFF_ERR    1245185ll
#define OFF_QLOW   1253377ll
#define OFF_QHIGH  1843201ll

__device__ inline short f2bf_s(float f) {
    __hip_bfloat16 h = __float2bfloat16(f);
    return __builtin_bit_cast(short, h);
}
// monotone fp32 -> u32 map (order-preserving)
__device__ inline unsigned mono(float f) {
    unsigned u = __builtin_bit_cast(unsigned, f);
    return (u & 0x80000000u) ? ~u : (u | 0x80000000u);
}
__device__ inline unsigned umin_(unsigned a, unsigned b) { return a < b ? a : b; }
__device__ inline unsigned umax_(unsigned a, unsigned b) { return a > b ? a : b; }

// ---------------------------------------------------------------------------
// Kernel A: fused MLP + LayerNorm + projection. 256 threads (4 waves),
// 16 rows/block, grid 1024. Activations in LDS; x broadcast via uniform
// ds_read_b128; weights streamed coalesced. Column-split across waves for
// 400/512-wide layers; row-split for L4+LN. FROZEN at R14 (best measured).
// ---------------------------------------------------------------------------

template<int IN_W, int NCC>
__device__ __forceinline__ void mlp_layer_acc(
    const float* __restrict__ W, const float* __restrict__ act,
    const int w, const int t, float (&acc)[ROWS][2])
{
    int jm[2];
    #pragma unroll
    for (int cc = 0; cc < NCC; ++cc) {
        const int j = w*128 + cc*64 + t;
        jm[cc] = (j < 400) ? j : 399;      // clamped dummy (discarded at store)
    }
    #pragma unroll
    for (int r = 0; r < ROWS; ++r)
        #pragma unroll
        for (int cc = 0; cc < NCC; ++cc) acc[r][cc] = 0.f;

    #pragma unroll 2
    for (int i4 = 0; i4 < IN_W/4; ++i4) {
        float wv[4][2];
        #pragma unroll
        for (int jj = 0; jj < 4; ++jj)
            #pragma unroll
            for (int cc = 0; cc < NCC; ++cc)
                wv[jj][cc] = W[(i4*4 + jj)*400 + jm[cc]];
        #pragma unroll
        for (int r = 0; r < ROWS; ++r) {
            const float4v xv = *(const float4v*)(act + r*AST + i4*4);
            #pragma unroll
            for (int jj = 0; jj < 4; ++jj)
                #pragma unroll
                for (int cc = 0; cc < NCC; ++cc)
                    acc[r][cc] = fmaf(xv[jj], wv[jj][cc], acc[r][cc]);
        }
    }
}

__device__ __forceinline__ void mlp_layer_store(
    const float* __restrict__ b, float* __restrict__ act,
    const int w, const int t, const int ncc, const float (&acc)[ROWS][2])
{
    #pragma unroll
    for (int cc = 0; cc < 2; ++cc) {          // static cc -> no scratch
        const int j = w*128 + cc*64 + t;
        if (cc < ncc && j < 400) {
            const float bv = b[j];
            #pragma unroll
            for (int r = 0; r < ROWS; ++r)
                act[r*AST + j] = fmaxf(acc[r][cc] + bv, 0.f);
        }
    }
}

__global__ __launch_bounds__(256, 4) void k_mlp(
    const float* __restrict__ Xt, const float* __restrict__ Xs,
    const float* __restrict__ W1, const float* __restrict__ b1,
    const float* __restrict__ W2, const float* __restrict__ b2,
    const float* __restrict__ W3, const float* __restrict__ b3,
    const float* __restrict__ W4, const float* __restrict__ b4,
    const float* __restrict__ Wq, const float* __restrict__ bq,
    const float* __restrict__ Wk, const float* __restrict__ bk,
    const float* __restrict__ g_q, const float* __restrict__ beta_q,
    const float* __restrict__ g_k, const float* __restrict__ beta_k,
    float* __restrict__ qf, float* __restrict__ kf,
    __hip_bfloat16* __restrict__ khi)
{
    __shared__ float act[ROWS*AST];          // 25.6 KB

    const int tid  = threadIdx.x;
    const int t    = tid & 63;
    const int w    = tid >> 6;               // wave 0..3
    const int bi   = blockIdx.x;
    const int half = bi >> 9;                // 0:true/q 1:sim/k
    const int rbase = (bi & 511) * ROWS;
    const float* X = half ? Xs : Xt;

    // stage input rows (16 x 64, coalesced)
    #pragma unroll
    for (int u = 0; u < (ROWS*64)/256; ++u) {
        const int e = u*256 + tid;
        act[(e >> 6)*AST + (e & 63)] = X[(size_t)rbase*64 + e];
    }
    __syncthreads();

    float acc[ROWS][2];
    const int ncc = (w == 3) ? 1 : 2;        // wave3: cols 448..511 all dummy

    // ---- layer 1: 64 -> 400 (relu) ----
    if (w == 3) mlp_layer_acc<64,1>(W1, act, w, t, acc);
    else        mlp_layer_acc<64,2>(W1, act, w, t, acc);
    __syncthreads();
    mlp_layer_store(b1, act, w, t, ncc, acc);
    __syncthreads();

    // ---- layer 2: 400 -> 400 (relu) ----
    if (w == 3) mlp_layer_acc<400,1>(W2, act, w, t, acc);
    else        mlp_layer_acc<400,2>(W2, act, w, t, acc);
    __syncthreads();
    mlp_layer_store(b2, act, w, t, ncc, acc);
    __syncthreads();

    // ---- layer 3: 400 -> 400 (relu) ----
    if (w == 3) mlp_layer_acc<400,1>(W3, act, w, t, acc);
    else        mlp_layer_acc<400,2>(W3, act, w, t, acc);
    __syncthreads();
    mlp_layer_store(b3, act, w, t, ncc, acc);
    __syncthreads();

    // ---- layer 4: 400 -> 128 (no relu): lane owns col pair (t, 64+t),
    //      wave w rows 4w..4w+3 -- exact R13/R14 mapping/i-order. ----
    float2v a4[4];
    #pragma unroll
    for (int rr = 0; rr < 4; ++rr) a4[rr] = (float2v){0.f, 0.f};
    #pragma unroll 2
    for (int i4 = 0; i4 < 100; ++i4) {
        float wv0[4], wv1[4];
        #pragma unroll
        for (int jj = 0; jj < 4; ++jj) {
            wv0[jj] = W4[(i4*4 + jj)*128 + t];
            wv1[jj] = W4[(i4*4 + jj)*128 + 64 + t];
        }
        #pragma unroll
        for (int rr = 0; rr < 4; ++rr) {
            const float4v xv = *(const float4v*)(act + (w*4 + rr)*AST + i4*4);
            #pragma unroll
            for (int jj = 0; jj < 4; ++jj) {
                a4[rr][0] = fmaf(xv[jj], wv0[jj], a4[rr][0]);
                a4[rr][1] = fmaf(xv[jj], wv1[jj], a4[rr][1]);
            }
        }
    }
    {
        const float b40 = b4[t], b41 = b4[64 + t];
        #pragma unroll
        for (int rr = 0; rr < 4; ++rr) { a4[rr][0] += b40; a4[rr][1] += b41; }
    }
    __syncthreads();                         // all L4 reads of act complete

    // ---- LayerNorm over 128 (2 vals/lane, same 64-lane butterfly) ----
    {
        const float* g  = half ? g_k : g_q;
        const float* be = half ? beta_k : beta_q;
        const float gl0 = g[t],  gl1 = g[64 + t];
        const float bl0 = be[t], bl1 = be[64 + t];
        #pragma unroll
        for (int rr = 0; rr < 4; ++rr) {
            float s = a4[rr][0] + a4[rr][1];
            #pragma unroll
            for (int o = 32; o > 0; o >>= 1) s += __shfl_xor(s, o);
            const float mu = s * (1.f/128.f);
            const float d0 = a4[rr][0] - mu, d1 = a4[rr][1] - mu;
            float vs = d0*d0 + d1*d1;
            #pragma unroll
            for (int o = 32; o > 0; o >>= 1) vs += __shfl_xor(vs, o);
            const float rstd = rsqrtf(vs * (1.f/128.f) + 1e-5f);
            act[(w*4 + rr)*128 + t]      = d0*rstd*gl0 + bl0;
            act[(w*4 + rr)*128 + 64 + t] = d1*rstd*gl1 + bl1;
        }
    }
    __syncthreads();

    // ---- projection 128 -> 512, col-split (all cols real) ----
    {
        const float* Wp = half ? Wk : Wq;
        const float* bp = half ? bk : bq;
        float* of = half ? kf : qf;

        float accp[ROWS][2];
        #pragma unroll
        for (int r = 0; r < ROWS; ++r) { accp[r][0] = 0.f; accp[r][1] = 0.f; }
        #pragma unroll 2
        for (int i4 = 0; i4 < 32; ++i4) {
            float wv[4][2];
            #pragma unroll
            for (int jj = 0; jj < 4; ++jj)
                #pragma unroll
                for (int cc = 0; cc < 2; ++cc)
                    wv[jj][cc] = Wp[(i4*4 + jj)*512 + w*128 + cc*64 + t];
            #pragma unroll
            for (int r = 0; r < ROWS; ++r) {
                const float4v xv = *(const float4v*)(act + r*128 + i4*4);
                #pragma unroll
                for (int jj = 0; jj < 4; ++jj)
                    #pragma unroll
                    for (int cc = 0; cc < 2; ++cc)
                        accp[r][cc] = fmaf(xv[jj], wv[jj][cc], accp[r][cc]);
            }
        }

        float bpv[2];
        bpv[0] = bp[w*128 + t];
        bpv[1] = bp[w*128 + 64 + t];
        #pragma unroll
        for (int r = 0; r < ROWS; ++r) {
            const int gidx = rbase + r;
            const int bb = gidx >> 11, s = gidx & 2047;
            const int T = s >> 4, m16s = s & 15;
            #pragma unroll
            for (int cc = 0; cc < 2; ++cc) {
                const int j  = w*128 + cc*64 + t;
                const int hh = j >> 7, d = j & 127;
                const float v = accp[r][cc] + bpv[cc];
                const size_t dst = ((size_t)(bb*4 + hh)*2048 + s)*128 + d;
                of[dst] = v;
                if (half) {
                    const int ks = d >> 5, qd = (d & 31) >> 3, jj = d & 7;
                    const size_t so = (size_t)(bb*4 + hh)*262144
                                    + (size_t)T*2048 + ks*512 + qd*128 + m16s*8 + jj;
                    khi[so] = __float2bfloat16(v);
                }
            }
        }
    }
}

// ---------------------------------------------------------------------------
// Kernel B: MFMA scan over an m-quarter (512 cols). Per lane: two independent
// sorted depth-12 key lists (2-way ILP); owner (quad0) 8-way tournament merge
// -> top-24 -> wsk. khi fragment-swizzled (contiguous 1KB/wave loads).
// R23: cti loop unroll 2 -- next iter's loads+MFMA (matrix pipe) hoist over
// current iter's inserts (VALU pipe); insert order unchanged.
// ---------------------------------------------------------------------------
__global__ __launch_bounds__(256, 4) void k_scan(
    const float* __restrict__ qf, const __hip_bfloat16* __restrict__ khi,
    unsigned* __restrict__ wsk)
{
    __shared__ unsigned kd[64*97];     // 24.8KB; row stride 97 (odd) bank-safe

    const int tid   = threadIdx.x;
    const int stile = blockIdx.x;      // 0..31
    const int hb    = blockIdx.y;      // 0..15
    const int mq    = blockIdx.z;      // 0..3

    const int lane = tid & 63;
    const int w    = tid >> 6;
    const int m16  = lane & 15;
    const int quad = lane >> 4;

    const size_t slab = (size_t)hb * 2048;
    const __hip_bfloat16* slabp = khi + (size_t)hb * 262144;   // swizzled slab

    const int sg_my = stile*64 + w*16 + m16;

    // Q fragment (B operand): B[n=m16][k=quad*8+j+ks*32] = q[w*16+n][k]
    short8v bq_[4];
    {
        const float* qp = qf + (slab + sg_my)*128 + quad*8;
        #pragma unroll
        for (int ks = 0; ks < 4; ++ks) {
            const float4 x0 = *(const float4*)(qp + ks*32);
            const float4 x1 = *(const float4*)(qp + ks*32 + 4);
            short8v tt;
            tt[0]=f2bf_s(x0.x); tt[1]=f2bf_s(x0.y); tt[2]=f2bf_s(x0.z); tt[3]=f2bf_s(x0.w);
            tt[4]=f2bf_s(x1.x); tt[5]=f2bf_s(x1.y); tt[6]=f2bf_s(x1.z); tt[7]=f2bf_s(x1.w);
            bq_[ks] = tt;
        }
    }

    unsigned KA[12], KB[12];           // ascending; [0] = min
    #pragma unroll
    for (int n = 0; n < 12; ++n) { KA[n] = 0u; KB[n] = 0u; }

    #pragma unroll 2
    for (int cti = 0; cti < 32; ++cti) {
        const int T = mq*32 + cti;     // global 16-col tile id
        const __hip_bfloat16* kp = slabp + (size_t)T*2048 + lane*8;
        float4v acc = (float4v){0.f,0.f,0.f,0.f};
        #pragma unroll
        for (int ks = 0; ks < 4; ++ks) {
            const short8v ka = *(const short8v*)(kp + ks*512);
            acc = __builtin_amdgcn_mfma_f32_16x16x32_bf16(ka, bq_[ks], acc, 0, 0, 0);
        }
        const int cb = T*16 + quad*4;
        #pragma unroll
        for (int ph = 0; ph < 2; ++ph) {
            {   // KA insert: reg = ph
                const int m = cb + ph;
                unsigned key = (mono(acc[ph]) & 0xFFFFF800u) | (unsigned)m;
                key = (m == sg_my) ? 0u : key;
                KA[0] = umax_(KA[0], key);
                #pragma unroll
                for (int i = 0; i < 11; ++i) {
                    const unsigned a = KA[i], c = KA[i+1];
                    KA[i]   = umin_(a, c);
                    KA[i+1] = umax_(a, c);
                }
            }
            {   // KB insert: reg = 2+ph
                const int m = cb + 2 + ph;
                unsigned key = (mono(acc[2+ph]) & 0xFFFFF800u) | (unsigned)m;
                key = (m == sg_my) ? 0u : key;
                KB[0] = umax_(KB[0], key);
                #pragma unroll
                for (int i = 0; i < 11; ++i) {
                    const unsigned a = KB[i], c = KB[i+1];
                    KB[i]   = umin_(a, c);
                    KB[i+1] = umax_(a, c);
                }
            }
        }
    }

    // dump: per (row, quad) two desc 12-lists
    const int rr = w*16 + m16;
    #pragma unroll
    for (int n = 0; n < 12; ++n) {
        kd[rr*97 + (quad*2 + 0)*12 + n] = KA[11 - n];
        kd[rr*97 + (quad*2 + 1)*12 + n] = KB[11 - n];
    }
    __syncthreads();

    // owner (quad 0): 8-way tournament merge -> top-24 -> ws (desc).
    if (quad == 0) {
        const unsigned* R = &kd[rr*97];
        int q0=0,q1=0,q2=0,q3=0,q4=0,q5=0,q6=0,q7=0;
        const size_t base = (size_t)hb*2048 + stile*64 + rr;
        #pragma unroll 1
        for (int n = 0; n < 24; ++n) {
            const unsigned h0 = (q0<12)?R[  0+q0]:0u;
            const unsigned h1 = (q1<12)?R[ 12+q1]:0u;
            const unsigned h2 = (q2<12)?R[ 24+q2]:0u;
            const unsigned h3 = (q3<12)?R[ 36+q3]:0u;
            const unsigned h4 = (q4<12)?R[ 48+q4]:0u;
            const unsigned h5 = (q5<12)?R[ 60+q5]:0u;
            const unsigned h6 = (q6<12)?R[ 72+q6]:0u;
            const unsigned h7 = (q7<12)?R[ 84+q7]:0u;
            unsigned bv = h0; int bs = 0;
            if (h1 > bv) { bv = h1; bs = 1; }
            if (h2 > bv) { bv = h2; bs = 2; }
            if (h3 > bv) { bv = h3; bs = 3; }
            if (h4 > bv) { bv = h4; bs = 4; }
            if (h5 > bv) { bv = h5; bs = 5; }
            if (h6 > bv) { bv = h6; bs = 6; }
            if (h7 > bv) { bv = h7; bs = 7; }
            q0 += (bs==0); q1 += (bs==1); q2 += (bs==2); q3 += (bs==3);
            q4 += (bs==4); q5 += (bs==5); q6 += (bs==6); q7 += (bs==7);
            wsk[(size_t)(mq*24 + n)*32768 + base] = bv;
        }
    }
}

// ---------------------------------------------------------------------------
// Kernel C: per row merge 4x24 approx keys -> top-32 -> cooperative exact
// fp32 rescore (pk-packed partials) -> exact top-20 -> quantiles + outputs.
// R23: wsk-load loop unroll 4 (independent loads); rescore loop unroll 2
// (two independent column-dots in flight at 2 waves/SIMD occupancy).
// ---------------------------------------------------------------------------
__global__ __launch_bounds__(256, 4) void k_select(
    const float* __restrict__ qf, const float* __restrict__ kf,
    const unsigned* __restrict__ wsk,
    const float* __restrict__ errors, const float* __restrict__ y,
    const float* __restrict__ y_pred,
    float* __restrict__ out, float* __restrict__ hacc)
{
    __shared__ unsigned kd[64*4*25];       // 25.6KB (pad 25)
    __shared__ unsigned short cb[64*33];   // 4.2KB candidate cols
    __shared__ float es[64*33];            // 8.4KB exact scores
    __shared__ float ebuf[64*21];          // 5.4KB sort buffer

    const int tid   = threadIdx.x;
    const int stile = blockIdx.x;          // 0..31
    const int hb    = blockIdx.y;          // 0..15
    const int b     = hb >> 2;
    const int h     = hb & 3;

    const int lane = tid & 63;
    const int w    = tid >> 6;
    const int m16  = lane & 15;
    const int quad = lane >> 4;
    const int rr   = w*16 + m16;
    const int sg   = stile*64 + rr;

    const size_t base = (size_t)hb*2048 + sg;
    #pragma unroll 4
    for (int n = 0; n < 24; ++n)
        kd[(rr*4 + quad)*25 + n] = wsk[(size_t)(quad*24 + n)*32768 + base];
    __syncthreads();

    // owner: merge 4 sorted-desc 24-lists -> approx-top-32 cols
    if (quad == 0) {
        const unsigned* L0 = &kd[(rr*4 + 0)*25];
        const unsigned* L1 = &kd[(rr*4 + 1)*25];
        const unsigned* L2 = &kd[(rr*4 + 2)*25];
        const unsigned* L3 = &kd[(rr*4 + 3)*25];
        int p0 = 0, p1 = 0, p2 = 0, p3 = 0;
        #pragma unroll 1
        for (int n = 0; n < 32; ++n) {
            const unsigned h0 = (p0 < 24) ? L0[p0] : 0u;
            const unsigned h1 = (p1 < 24) ? L1[p1] : 0u;
            const unsigned h2 = (p2 < 24) ? L2[p2] : 0u;
            const unsigned h3 = (p3 < 24) ? L3[p3] : 0u;
            unsigned bv = h0; int bs = 0;
            if (h1 > bv) { bv = h1; bs = 1; }
            if (h2 > bv) { bv = h2; bs = 2; }
            if (h3 > bv) { bv = h3; bs = 3; }
            if (bs == 0) ++p0; else if (bs == 1) ++p1; else if (bs == 2) ++p2; else ++p3;
            cb[rr*33 + n] = (unsigned short)(bv & 0x7FFu);
        }
    }
    __syncthreads();

    // cooperative exact rescore of the 32 candidates (pk-packed partials)
    const size_t slab = (size_t)hb * 2048;
    const float* qrow_p = qf + (slab + sg)*128;
    float4 qseg[8];
    #pragma unroll
    for (int u = 0; u < 8; ++u)
        qseg[u] = *(const float4*)(qrow_p + quad*4 + u*16);
    const float* kslab = kf + slab*128;
    #pragma unroll 2
    for (int n = 0; n < 32; ++n) {
        const int col = cb[rr*33 + n];
        const float* kc = kslab + (size_t)col*128 + quad*4;
        float2v s01 = (float2v){0.f, 0.f}, s23 = (float2v){0.f, 0.f};
        #pragma unroll
        for (int u = 0; u < 8; ++u) {
            const float4 kv = *(const float4*)(kc + u*16);
            s01 = __builtin_elementwise_fma((float2v){qseg[u].x, qseg[u].y},
                                            (float2v){kv.x, kv.y}, s01);
            s23 = __builtin_elementwise_fma((float2v){qseg[u].z, qseg[u].w},
                                            (float2v){kv.z, kv.w}, s23);
        }
        float v = (s01[0] + s01[1]) + (s23[0] + s23[1]);
        v += __shfl_xor(v, 16);
        v += __shfl_xor(v, 32);
        if (quad == 0) es[rr*33 + n] = v;
    }

    // owner: exact top-20 selection (desc, col asc ties) + quantiles
    float sq = 0.f;
    if (quad == 0) {
        float* e = &ebuf[rr*21];
        #pragma unroll 1
        for (int k = 0; k < 20; ++k) {
            float best = -INFINITY; int bc = 4096, bj = 0;
            #pragma unroll 1
            for (int j = 0; j < 32; ++j) {
                const float v = es[rr*33 + j];
                const int c = cb[rr*33 + j];
                if (v > best || (v == best && c < bc)) { best = v; bc = c; bj = j; }
            }
            es[rr*33 + bj] = -INFINITY;
            e[k] = errors[((size_t)(b*SS + bc))*4];   // errors[..., 0]
        }
        #pragma unroll 1
        for (int a = 1; a < 20; ++a) {     // insertion sort ascending
            const float v = e[a];
            int n = a;
            while (n > 0 && e[n-1] > v) { e[n] = e[n-1]; --n; }
            e[n] = v;
        }
        const float yp = y_pred[((size_t)(b*SS + sg))*4];
        const float yt = y[((size_t)(b*SS + sg))*4];
        float msum = 0.f;
        const size_t obase = ((size_t)(h*4 + b)*18)*2048 + sg;
        #pragma unroll 1
        for (int a = 0; a < 18; ++a) {
            const float alpha = c_alphas[a];
            const float beta  = 0.5f*alpha;
            const float pl = beta * 19.f;
            const int   il = (int)pl;
            const float fl = pl - (float)il;
            const float ql = e[il]*(1.f-fl) + e[il+1]*fl;
            const float qq = (1.f - alpha) + beta;
            const float ph = qq * 19.f;
            const int   ih = (int)ph;
            const float fh = ph - (float)ih;
            const float qh = e[ih]*(1.f-fh) + e[ih+1]*fh;
            msum += ql + qh;
            const size_t oidx = obase + (size_t)a*2048;
            out[OFF_YLOW  + oidx] = ql + yp;
            out[OFF_YHIGH + oidx] = qh + yp;
            out[OFF_QLOW  + oidx] = ql;
            out[OFF_QHIGH + oidx] = qh;
        }
        const float me = msum * (1.f/36.f);
        const float dd = yt - (me + yp);
        sq = dd*dd;
    }
    // wave-reduce sq (non-owners contribute 0), one atomic per wave
    #pragma unroll
    for (int o = 32; o > 0; o >>= 1) sq += __shfl_xor(sq, o);
    if (lane == 0) atomicAdd(&hacc[h], sq);
}

__global__ void k_init(float* __restrict__ hacc) {
    if (threadIdx.x < 4) hacc[threadIdx.x] = 0.f;
}

__global__ __launch_bounds__(256) void k_finalize(
    const float* __restrict__ y, const float* __restrict__ y_pred,
    const float* __restrict__ errors, const float* __restrict__ hacc,
    float* __restrict__ out)
{
    const int i = blockIdx.x*256 + threadIdx.x;
    if (i == 0)
        out[0] = (hacc[0]+hacc[1]+hacc[2]+hacc[3]) * (1.f/32768.f);
    if (i < 32768)      out[OFF_Y + i] = y[i];
    else if (i < 65536) out[OFF_YPRED + (i - 32768)] = y_pred[i - 32768];
    else if (i < 73728) { const int j = i - 65536; out[OFF_ERR + j] = errors[(size_t)j*4]; }
}

extern "C" void kernel_launch(void* const* d_in, const int* in_sizes, int n_in,
                              void* d_out, int out_size, void* d_ws, size_t ws_size,
                              hipStream_t stream)
{
    const float* Xt     = (const float*)d_in[0];
    const float* Xs     = (const float*)d_in[1];
    const float* errors = (const float*)d_in[2];
    const float* y      = (const float*)d_in[3];
    const float* y_pred = (const float*)d_in[4];
    const float* W1 = (const float*)d_in[5];   const float* b1 = (const float*)d_in[6];
    const float* W2 = (const float*)d_in[7];   const float* b2 = (const float*)d_in[8];
    const float* W3 = (const float*)d_in[9];   const float* b3 = (const float*)d_in[10];
    const float* W4 = (const float*)d_in[11];  const float* b4 = (const float*)d_in[12];
    const float* Wq = (const float*)d_in[13];  const float* bq = (const float*)d_in[14];
    const float* Wk = (const float*)d_in[15];  const float* bk = (const float*)d_in[16];
    const float* g_q    = (const float*)d_in[17];
    const float* beta_q = (const float*)d_in[18];
    const float* g_k    = (const float*)d_in[19];
    const float* beta_k = (const float*)d_in[20];

    float* out  = (float*)d_out;
    char*  base = (char*)d_ws;
    const size_t SLAB = (size_t)16*2048*128;               // 4,194,304 elements
    float* hacc = (float*)base;                            // 64B slot
    float* qf   = (float*)(base + 256);                    // 16MB
    float* kf   = qf + SLAB;                               // 16MB
    __hip_bfloat16* khi = (__hip_bfloat16*)(kf + SLAB);    // 8MB (swizzled)
    unsigned* wsk = (unsigned*)(khi + SLAB);               // 12.6MB

    k_init<<<1, 64, 0, stream>>>(hacc);
    k_mlp<<<1024, 256, 0, stream>>>(Xt, Xs, W1,b1,W2,b2,W3,b3,W4,b4,
                                    Wq,bq,Wk,bk,g_q,beta_q,g_k,beta_k,
                                    qf, kf, khi);
    k_scan<<<dim3(32,16,4), 256, 0, stream>>>(qf, khi, wsk);
    k_select<<<dim3(32,16), 256, 0, stream>>>(qf, kf, wsk, errors, y, y_pred, out, hacc);
    k_finalize<<<288, 256, 0, stream>>>(y, y_pred, errors, hacc, out);
}